// Round 10
// baseline (208.658 us; speedup 1.0000x reference)
//
#include <hip/hip_runtime.h>
#include <math.h>

constexpr int N  = 50000;
constexpr int E  = 400000;
constexpr int R  = 1000;
constexpr int K1 = 1000;
constexpr int F  = 128;
constexpr int OUTC = 256;
constexpr int P  = 64;

typedef _Float16 f16x8 __attribute__((ext_vector_type(8)));
typedef _Float16 f16x4 __attribute__((ext_vector_type(4)));
typedef _Float16 f16x2 __attribute__((ext_vector_type(2)));
typedef float f32x4 __attribute__((ext_vector_type(4)));

#if __has_builtin(__builtin_amdgcn_fdot2)
#define FDOT2(a, b, c) __builtin_amdgcn_fdot2((a), (b), (c), false)
#else
#define FDOT2(a, b, c) fmaf((float)(a)[0], (float)(b)[0], fmaf((float)(a)[1], (float)(b)[1], (c)))
#endif

__device__ inline float waveReduceSum(float v) {
#pragma unroll
    for (int m = 32; m >= 1; m >>= 1) v += __shfl_xor(v, m, 64);
    return v;
}

__device__ inline f16x8 ntload8(const f16x8* p) {
    return __builtin_nontemporal_load(p);
}

// ---------------- prep_a: featsh | relprep | seg | pscale | PGf ---------
constexpr int B_FEATSH = 3125;   // N*F/8 / 256
constexpr int B_REL    = 250;    // R/4 (wave per relation)
constexpr int B_SEG    = 1563;
constexpr int B_PSC    = 16;     // P/4 (wave per proxy row)
constexpr int B_PGF    = 64;     // one block per proxy row, coalesced over cols

__global__ __launch_bounds__(256) void prep_a(
        const float* __restrict__ feats, const float* __restrict__ rel_emb,
        const float* __restrict__ attn,  const float* __restrict__ proxy,
        const float* __restrict__ G,     const int* __restrict__ adj,
        _Float16* __restrict__ featsH,   _Float16* __restrict__ relnormH,
        float* __restrict__ dotr, int* __restrict__ nstart, int* __restrict__ nend,
        float* __restrict__ pscale, float* __restrict__ PGf) {
    int b = blockIdx.x, tid = threadIdx.x;
    if (b < B_FEATSH) {
        int idx = b * 256 + tid;
        float4 x0 = ((const float4*)feats)[2 * idx];
        float4 x1 = ((const float4*)feats)[2 * idx + 1];
        f16x8 h;
        h[0] = (_Float16)x0.x; h[1] = (_Float16)x0.y;
        h[2] = (_Float16)x0.z; h[3] = (_Float16)x0.w;
        h[4] = (_Float16)x1.x; h[5] = (_Float16)x1.y;
        h[6] = (_Float16)x1.z; h[7] = (_Float16)x1.w;
        ((f16x8*)featsH)[idx] = h;
    } else if (b < B_FEATSH + B_REL) {
        int r = (b - B_FEATSH) * 4 + (tid >> 6);
        int lane = tid & 63;
        float2 v  = ((const float2*)(rel_emb + (size_t)r * F))[lane];
        float2 a0 = ((const float2*)attn)[lane];
        float2 a1 = ((const float2*)attn)[64 + lane];
        float ss = waveReduceSum(v.x * v.x + v.y * v.y);
        float d0 = waveReduceSum(v.x * a0.x + v.y * a0.y);
        float d1 = waveReduceSum(v.x * a1.x + v.y * a1.y);
        float sc = rsqrtf(fmaxf(ss, 1e-12f));
        f16x2 h; h[0] = (_Float16)(v.x * sc); h[1] = (_Float16)(v.y * sc);
        ((f16x2*)(relnormH + (size_t)r * F))[lane] = h;
        if (lane == 0) { dotr[2 * r] = d0; dotr[2 * r + 1] = d1; }
    } else if (b < B_FEATSH + B_REL + B_SEG) {
        int e = (b - B_FEATSH - B_REL) * 256 + tid;
        if (e < E) {
            int lane = tid & 63;
            int row = ((const int2*)adj)[e].x;
            int prev = __shfl_up(row, 1, 64);
            if (lane == 0) prev = (e > 0) ? ((const int2*)adj)[e - 1].x : -1;
            int nxt = __shfl_down(row, 1, 64);
            if (lane == 63 && e + 1 < E) nxt = ((const int2*)adj)[e + 1].x;
            if (prev != row) {
                nstart[row] = e;
                for (int rr = prev + 1; rr < row; ++rr) { nstart[rr] = e; nend[rr] = e; }
            }
            if (e == E - 1) {
                nend[row] = E;
                for (int rr = row + 1; rr < N; ++rr) { nstart[rr] = E; nend[rr] = E; }
            } else if (nxt != row) {
                nend[row] = e + 1;
            }
        }
    } else if (b < B_FEATSH + B_REL + B_SEG + B_PSC) {
        int j = (b - B_FEATSH - B_REL - B_SEG) * 4 + (tid >> 6);
        int lane = tid & 63;
        float4 p = ((const float4*)(proxy + (size_t)j * OUTC))[lane];
        float ss = waveReduceSum(p.x * p.x + p.y * p.y + p.z * p.z + p.w * p.w);
        if (lane == 0) pscale[j] = rsqrtf(fmaxf(ss, 1e-12f));
    } else {
        // PGf[p][c] = sum_k proxy[p][k] * G[k][c]  (coalesced over c)
        int p = b - (B_FEATSH + B_REL + B_SEG + B_PSC);
        int c = tid;
        float s = 0.f;
        for (int k = 0; k < OUTC; ++k)
            s = fmaf(proxy[(size_t)p * OUTC + k], G[(size_t)k * OUTC + c], s);
        PGf[(size_t)p * OUTC + c] = s;
    }
}

// ---------------- node_aggregate + fragprep (merged grids) -----------------------
// B-frag 16x16x32: lane L holds B[k = kk*32 + (L>>4)*8 + j][n = base + (L&15)]
// Node-agg: 2 edges/group in flight (8 edges/wave-iteration). NOTE (R7 post-mortem):
// mean degree = 8, so 2 slots/group are both real edges; 4-deep slots are clamped
// duplicates -> 50% wasted gathers+VALU (measured +25% duration). Keep 2-deep.
constexpr int NB_NODE = N / 4;   // 12500
constexpr int NB_FRAG = 56;      // 224 64-lane units / 4

__global__ __launch_bounds__(256) void node_frag(
        const _Float16* __restrict__ featsH,
        const _Float16* __restrict__ relnormH,
        const float* __restrict__ dotr,
        const int* __restrict__ adj,
        const int* __restrict__ sidx,
        const float* __restrict__ val,
        const int* __restrict__ nstart,
        const int* __restrict__ nend,
        const float* __restrict__ G,
        const float* __restrict__ proxy,
        const float* __restrict__ pscale,
        const float* __restrict__ PGf,
        _Float16* __restrict__ nf0,
        _Float16* __restrict__ nf1,
        f16x8* __restrict__ Gh, f16x8* __restrict__ pnH,
        f16x8* __restrict__ pxH, f16x8* __restrict__ pgH) {
    if (blockIdx.x >= NB_NODE) {
        // ---- fragprep ----
        int u = (blockIdx.x - NB_NODE) * 4 + (threadIdx.x >> 6);  // 0..223
        int L = threadIdx.x & 63;
        int q = L >> 4, m = L & 15;
        f16x8 h;
        if (u < 128) {                               // Gh: G (256x256)
            int kk = u >> 4, cg = u & 15;
            int n = cg * 16 + m;
#pragma unroll
            for (int j = 0; j < 8; ++j)
                h[j] = (_Float16)G[(size_t)(kk * 32 + q * 8 + j) * OUTC + n];
            Gh[(size_t)u * 64 + L] = h;
        } else if (u < 160) {                        // pnH: l2n(proxy)^T (256x64)
            int idx = u - 128;
            int kk = idx >> 2, w = idx & 3;
            int n = w * 16 + m;
            float sc = pscale[n];
#pragma unroll
            for (int j = 0; j < 8; ++j)
                h[j] = (_Float16)(proxy[(size_t)n * OUTC + kk * 32 + q * 8 + j] * sc);
            pnH[(size_t)idx * 64 + L] = h;
        } else if (u < 192) {                        // pxH: proxy (64x256)
            int idx = u - 160;
            int kk = idx >> 4, cg = idx & 15;
            int n = cg * 16 + m;
#pragma unroll
            for (int j = 0; j < 8; ++j)
                h[j] = (_Float16)proxy[(size_t)(kk * 32 + q * 8 + j) * OUTC + n];
            pxH[(size_t)idx * 64 + L] = h;
        } else {                                     // pgH: -(proxy@G) from PGf
            int idx = u - 192;
            int kk = idx >> 4, cg = idx & 15;
            int n = cg * 16 + m;
#pragma unroll
            for (int j = 0; j < 8; ++j)
                h[j] = (_Float16)(-PGf[(size_t)(kk * 32 + q * 8 + j) * OUTC + n]);
            pgH[(size_t)idx * 64 + L] = h;
        }
        return;
    }
    // ---- node aggregation: single pass, normalize at end ----
    int n = blockIdx.x * 4 + (threadIdx.x >> 6);
    int lane = threadIdx.x & 63;
    int g = lane >> 4, gl = lane & 15;
    int start = nstart[n], end = nend[n];
    const int2* adj2 = (const int2*)adj;
    const int2* sx2  = (const int2*)sidx;
    float A0[8], A1[8];
#pragma unroll
    for (int j = 0; j < 8; ++j) { A0[j] = 0.f; A1[j] = 0.f; }
    float s0 = 0.f, s1 = 0.f;
    for (int e = start + g; e < end; e += 8) {
        int eB = e + 4;
        bool hasB = (eB < end);
        int eBc = hasB ? eB : e;
        int colA = adj2[e].y,   colB = adj2[eBc].y;
        int relA = sx2[e].y,    relB = sx2[eBc].y;
        float vA = val[e],      vB = val[eBc];
        float2 drA = ((const float2*)dotr)[relA];
        float2 drB = ((const float2*)dotr)[relB];
        float wA0 = __expf(vA * drA.x), wA1 = __expf(vA * drA.y);
        float wB0 = hasB ? __expf(vB * drB.x) : 0.f;
        float wB1 = hasB ? __expf(vB * drB.y) : 0.f;
        s0 += wA0 + wB0; s1 += wA1 + wB1;
        f16x8 fAv = ((const f16x8*)(featsH   + (size_t)colA * F))[gl];
        f16x8 rAv = ((const f16x8*)(relnormH + (size_t)relA * F))[gl];
        f16x8 fBv = ((const f16x8*)(featsH   + (size_t)colB * F))[gl];
        f16x8 rBv = ((const f16x8*)(relnormH + (size_t)relB * F))[gl];
        const f16x2* fA2 = (const f16x2*)&fAv;
        const f16x2* rA2 = (const f16x2*)&rAv;
        const f16x2* fB2 = (const f16x2*)&fBv;
        const f16x2* rB2 = (const f16x2*)&rBv;
        float pdA = 0.f, pdB = 0.f;
#pragma unroll
        for (int j = 0; j < 4; ++j) {
            pdA = FDOT2(fA2[j], rA2[j], pdA);
            pdB = FDOT2(fB2[j], rB2[j], pdB);
        }
        pdA += __shfl_xor(pdA, 1, 64); pdB += __shfl_xor(pdB, 1, 64);
        pdA += __shfl_xor(pdA, 2, 64); pdB += __shfl_xor(pdB, 2, 64);
        pdA += __shfl_xor(pdA, 4, 64); pdB += __shfl_xor(pdB, 4, 64);
        pdA += __shfl_xor(pdA, 8, 64); pdB += __shfl_xor(pdB, 8, 64);
        _Float16 tAh = (_Float16)(2.f * pdA), tBh = (_Float16)(2.f * pdB);
        f16x2 tA2; tA2[0] = tAh; tA2[1] = tAh;
        f16x2 tB2; tB2[0] = tBh; tB2[1] = tBh;
#pragma unroll
        for (int j = 0; j < 4; ++j) {
            f16x2 rxA = fA2[j] - tA2 * rA2[j];
            f16x2 rxB = fB2[j] - tB2 * rB2[j];
            float x0 = (float)rxA[0], x1 = (float)rxA[1];
            float y0 = (float)rxB[0], y1 = (float)rxB[1];
            A0[2*j]   = fmaf(wA0, x0, A0[2*j]);   A0[2*j]   = fmaf(wB0, y0, A0[2*j]);
            A0[2*j+1] = fmaf(wA0, x1, A0[2*j+1]); A0[2*j+1] = fmaf(wB0, y1, A0[2*j+1]);
            A1[2*j]   = fmaf(wA1, x0, A1[2*j]);   A1[2*j]   = fmaf(wB1, y0, A1[2*j]);
            A1[2*j+1] = fmaf(wA1, x1, A1[2*j+1]); A1[2*j+1] = fmaf(wB1, y1, A1[2*j+1]);
        }
    }
#pragma unroll
    for (int j = 0; j < 8; ++j) {
        A0[j] += __shfl_xor(A0[j], 16, 64); A0[j] += __shfl_xor(A0[j], 32, 64);
        A1[j] += __shfl_xor(A1[j], 16, 64); A1[j] += __shfl_xor(A1[j], 32, 64);
    }
    s0 += __shfl_xor(s0, 16, 64); s0 += __shfl_xor(s0, 32, 64);
    s1 += __shfl_xor(s1, 16, 64); s1 += __shfl_xor(s1, 32, 64);
    float i0 = (s0 > 0.f) ? 1.f / s0 : 0.f;
    float i1 = (s1 > 0.f) ? 1.f / s1 : 0.f;
    if (g == 0) {
        f16x8 h0, h1;
#pragma unroll
        for (int j = 0; j < 8; ++j) {
            h0[j] = (_Float16)(A0[j] * i0);
            h1[j] = (_Float16)(A1[j] * i1);
        }
        ((f16x8*)(nf0 + (size_t)n * F))[gl] = h0;
        ((f16x8*)(nf1 + (size_t)n * F))[gl] = h1;
    }
}

// ---------------- F: fused build + proxy attention + gate, 64 rows / 512 thr -----
// RT=4, 8 waves [R6 structure] + R9 changes:
//  (a) attH aliases attL (dead after softmax read; barrier-protected 2-phase
//      softmax) -> LDS 59.6 -> 50.4 KB -> 3 blocks/CU (24 waves, 75% theor. occ).
//  (b) nontemporal loads for featsH/nf0/nf1 streams + nontemporal out stores:
//      keeps the read/write streams out of L2 so the 224 KB fragment set stays
//      resident (every block re-reads it).
__global__ __launch_bounds__(512, 6) void proxy_gate(
        const _Float16* __restrict__ featsH,
        const _Float16* __restrict__ nf0,
        const _Float16* __restrict__ nf1,
        const int* __restrict__ neigh,
        const f16x8* __restrict__ pnH,
        const f16x8* __restrict__ pxH,
        const f16x8* __restrict__ Gh,
        const f16x8* __restrict__ pgH,
        float* __restrict__ out) {
    constexpr int RT   = 4;
    constexpr int LDA  = 68;   // f32 logits stride (floats)
    constexpr int LDAH = 72;   // f16 att stride (halves); 144B rows, 16B-aligned
    __shared__ __align__(16) f16x8 outH[RT * 8 * 64];        // 32 KB, A-frag order
    __shared__ __align__(16) float attL[RT * 16 * LDA];      // 17.4 KB (reused as attH)
    __shared__ float scaleL[RT * 16];
    _Float16* attH = (_Float16*)attL;   // alias: attL dead after softmax read phase
    int tid = threadIdx.x;                            // 0..511
    int w = tid >> 6, lane = tid & 63;                // w: 0..7
    int quad = lane >> 4, m = lane & 15;
    size_t row0 = (size_t)blockIdx.x * (RT * 16);

    // ---- build tiles -> f16 A-frags + row 1/norm (2 rows per thread, nt loads) ----
    {
        int bm0 = tid >> 4, gl = tid & 15;
#pragma unroll
        for (int half = 0; half < 2; ++half) {
            int bm = bm0 + 32 * half;                 // 0..63
            int n = (int)row0 + bm;
            float ss;
            f16x8 h1, h2;
            if (n < N) {
                ss = 0.f;
                h1 = ntload8((const f16x8*)(featsH + (size_t)n * F) + gl);
#pragma unroll
                for (int j = 0; j < 8; ++j) { float x = (float)h1[j]; ss += x * x; }
                int sel = (n < K1) ? neigh[n] : n;
                f16x8 a  = ntload8((const f16x8*)(nf0 + (size_t)n   * F) + gl);
                f16x8 b2 = ntload8((const f16x8*)(nf1 + (size_t)sel * F) + gl);
#pragma unroll
                for (int j = 0; j < 8; ++j) {
                    float v = 0.5f * ((float)a[j] + (float)b2[j]);
                    h2[j] = (_Float16)v;
                    ss += v * v;
                }
            } else {
#pragma unroll
                for (int j = 0; j < 8; ++j) { h1[j] = (_Float16)0.f; h2[j] = (_Float16)0.f; }
                ss = 1.f;
            }
            int t = bm >> 4, r16 = bm & 15;
            outH[(t * 8 +     (gl >> 2)) * 64 + (gl & 3) * 16 + r16] = h1;
            outH[(t * 8 + 4 + (gl >> 2)) * 64 + (gl & 3) * 16 + r16] = h2;
            ss += __shfl_xor(ss, 1, 64); ss += __shfl_xor(ss, 2, 64);
            ss += __shfl_xor(ss, 4, 64); ss += __shfl_xor(ss, 8, 64);
            if (gl == 0) scaleL[bm] = rsqrtf(fmaxf(ss, 1e-12f));
        }
    }
    __syncthreads();

    // ---- logits + z = out@G.  Wave w: logits tasks (tl0,pg) & (tl0+2,pg);
    //      z cols cg in {w, w+8} across all 4 tiles. ----
    int tl0 = w >> 2;       // 0 or 1; second task tile = tl0+2
    int pg = w & 3;
    f32x4 lacc[2] = {(f32x4){0,0,0,0}, (f32x4){0,0,0,0}};
    f32x4 zacc[RT][2];
#pragma unroll
    for (int t = 0; t < RT; ++t)
#pragma unroll
        for (int c = 0; c < 2; ++c) zacc[t][c] = (f32x4){0,0,0,0};
#pragma unroll
    for (int kk = 0; kk < 8; ++kk) {
        f16x8 pb  = pnH[(size_t)(kk * 4 + pg) * 64 + lane];
        f16x8 gb0 = Gh[(size_t)(kk * 16 + w)     * 64 + lane];
        f16x8 gb1 = Gh[(size_t)(kk * 16 + w + 8) * 64 + lane];
        f16x8 a0 = outH[(0 * 8 + kk) * 64 + lane];
        f16x8 a1 = outH[(1 * 8 + kk) * 64 + lane];
        f16x8 a2 = outH[(2 * 8 + kk) * 64 + lane];
        f16x8 a3 = outH[(3 * 8 + kk) * 64 + lane];
        f16x8 aL0 = tl0 ? a1 : a0;   // wave-uniform
        f16x8 aL1 = tl0 ? a3 : a2;
        lacc[0]    = __builtin_amdgcn_mfma_f32_16x16x32_f16(aL0, pb,  lacc[0],    0, 0, 0);
        lacc[1]    = __builtin_amdgcn_mfma_f32_16x16x32_f16(aL1, pb,  lacc[1],    0, 0, 0);
        zacc[0][0] = __builtin_amdgcn_mfma_f32_16x16x32_f16(a0, gb0, zacc[0][0], 0, 0, 0);
        zacc[0][1] = __builtin_amdgcn_mfma_f32_16x16x32_f16(a0, gb1, zacc[0][1], 0, 0, 0);
        zacc[1][0] = __builtin_amdgcn_mfma_f32_16x16x32_f16(a1, gb0, zacc[1][0], 0, 0, 0);
        zacc[1][1] = __builtin_amdgcn_mfma_f32_16x16x32_f16(a1, gb1, zacc[1][1], 0, 0, 0);
        zacc[2][0] = __builtin_amdgcn_mfma_f32_16x16x32_f16(a2, gb0, zacc[2][0], 0, 0, 0);
        zacc[2][1] = __builtin_amdgcn_mfma_f32_16x16x32_f16(a2, gb1, zacc[2][1], 0, 0, 0);
        zacc[3][0] = __builtin_amdgcn_mfma_f32_16x16x32_f16(a3, gb0, zacc[3][0], 0, 0, 0);
        zacc[3][1] = __builtin_amdgcn_mfma_f32_16x16x32_f16(a3, gb1, zacc[3][1], 0, 0, 0);
    }
#pragma unroll
    for (int u = 0; u < 2; ++u) {
        int tile = tl0 + 2 * u;
#pragma unroll
        for (int i = 0; i < 4; ++i) {
            int r = tile * 16 + quad * 4 + i;
            attL[r * LDA + pg * 16 + m] = lacc[u][i] * scaleL[r];
        }
    }
    __syncthreads();

    // ---- softmax over 64 proxies; read attL -> regs; barrier; write f16 attH ----
    {
        float av[8];
#pragma unroll
        for (int i = 0; i < 8; ++i) {
            int r = 8 * w + i;
            float e = __expf(attL[r * LDA + lane]);
            float s = waveReduceSum(e);
            av[i] = e / s;
        }
        __syncthreads();   // all attL reads done before attH overwrites the buffer
#pragma unroll
        for (int i = 0; i < 8; ++i) {
            int r = 8 * w + i;
            attH[r * LDAH + lane] = (_Float16)av[i];
        }
    }
    __syncthreads();

    // ---- q = att@proxy ; z -= att@PG  (wave w: cg in {w, w+8}, 4 tiles) ----
    f32x4 qacc[RT][2];
#pragma unroll
    for (int t = 0; t < RT; ++t)
#pragma unroll
        for (int c = 0; c < 2; ++c) qacc[t][c] = (f32x4){0,0,0,0};
#pragma unroll
    for (int kk = 0; kk < 2; ++kk) {
        f16x8 a[RT];
#pragma unroll
        for (int t = 0; t < RT; ++t)
            a[t] = *(const f16x8*)&attH[(t * 16 + m) * LDAH + kk * 32 + quad * 8];
#pragma unroll
        for (int cgi = 0; cgi < 2; ++cgi) {
            int cg = w + 8 * cgi;
            f16x8 bx = pxH[(size_t)(kk * 16 + cg) * 64 + lane];
            f16x8 bg = pgH[(size_t)(kk * 16 + cg) * 64 + lane];
#pragma unroll
            for (int t = 0; t < RT; ++t) {
                qacc[t][cgi] = __builtin_amdgcn_mfma_f32_16x16x32_f16(a[t], bx, qacc[t][cgi], 0, 0, 0);
                zacc[t][cgi] = __builtin_amdgcn_mfma_f32_16x16x32_f16(a[t], bg, zacc[t][cgi], 0, 0, 0);
            }
        }
    }

    // ---- epilogue: ov from LDS (f16), gate, nontemporal store ----
    const _Float16* outHs = (const _Float16*)outH;
#pragma unroll
    for (int t = 0; t < RT; ++t) {
        if ((int)row0 + t * 16 >= N) continue;
#pragma unroll
        for (int cgi = 0; cgi < 2; ++cgi) {
            int cg = w + 8 * cgi;
            int c = cg * 16 + m;
            int kkc = cg >> 1;
            int qc = ((cg & 1) << 1) | (m >> 3);
            int j = m & 7;
#pragma unroll
            for (int i = 0; i < 4; ++i) {
                int r15 = quad * 4 + i;
                float ov = (float)outHs[(((t * 8 + kkc) * 64 + qc * 16 + r15) << 3) + j];
                float gate = 1.f / (1.f + __expf(-zacc[t][cgi][i]));
                size_t n = row0 + t * 16 + r15;
                __builtin_nontemporal_store(ov - (1.f - gate) * qacc[t][cgi][i],
                                            &out[n * OUTC + c]);
            }
        }
    }
}

extern "C" void kernel_launch(void* const* d_in, const int* in_sizes, int n_in,
                              void* d_out, int out_size, void* d_ws, size_t ws_size,
                              hipStream_t stream) {
    const float* features   = (const float*)d_in[0];
    const float* rel_emb    = (const float*)d_in[1];
    const float* sparse_val = (const float*)d_in[2];
    const float* attn       = (const float*)d_in[3];
    const float* proxy      = (const float*)d_in[4];
    const float* gateK      = (const float*)d_in[5];
    const int*   adj        = (const int*)d_in[6];
    const int*   sidx       = (const int*)d_in[7];
    const int*   neigh      = (const int*)d_in[9];
    float* out = (float*)d_out;

    char* ws = (char*)d_ws;
    size_t off = 0;
    auto alloc = [&](size_t bytes) -> void* {
        void* p = ws + off;
        off += (bytes + 255) & ~(size_t)255;
        return p;
    };
    _Float16* relnormH = (_Float16*)alloc((size_t)R * F * 2);
    float*    dotr     = (float*)alloc((size_t)R * 2 * 4);
    float*    pscale   = (float*)alloc((size_t)P * 4);
    float*    PGf      = (float*)alloc((size_t)P * OUTC * 4);
    f16x8*    Gh       = (f16x8*)alloc((size_t)128 * 64 * 16);
    f16x8*    pnH      = (f16x8*)alloc((size_t)32 * 64 * 16);
    f16x8*    pxH      = (f16x8*)alloc((size_t)32 * 64 * 16);
    f16x8*    pgH      = (f16x8*)alloc((size_t)32 * 64 * 16);
    _Float16* featsH   = (_Float16*)alloc((size_t)N * F * 2);
    int*      nstart   = (int*)alloc((size_t)N * 4);
    int*      nend     = (int*)alloc((size_t)N * 4);
    _Float16* nf0      = (_Float16*)alloc((size_t)N * F * 2);
    _Float16* nf1      = (_Float16*)alloc((size_t)N * F * 2);

    prep_a<<<B_FEATSH + B_REL + B_SEG + B_PSC + B_PGF, 256, 0, stream>>>(
        features, rel_emb, attn, proxy, gateK, adj,
        featsH, relnormH, dotr, nstart, nend, pscale, PGf);
    node_frag<<<NB_NODE + NB_FRAG, 256, 0, stream>>>(
        featsH, relnormH, dotr, adj, sidx, sparse_val, nstart, nend,
        gateK, proxy, pscale, PGf,
        nf0, nf1, Gh, pnH, pxH, pgH);
    proxy_gate<<<(N + 63) / 64, 512, 0, stream>>>(
        featsH, nf0, nf1, neigh, pnH, pxH, Gh, pgH, out);
}

// Round 11
// 200.097 us; speedup vs baseline: 1.0428x; 1.0428x over previous
//
#include <hip/hip_runtime.h>
#include <math.h>

constexpr int N  = 50000;
constexpr int E  = 400000;
constexpr int R  = 1000;
constexpr int K1 = 1000;
constexpr int F  = 128;
constexpr int OUTC = 256;
constexpr int P  = 64;

typedef _Float16 f16x8 __attribute__((ext_vector_type(8)));
typedef _Float16 f16x4 __attribute__((ext_vector_type(4)));
typedef _Float16 f16x2 __attribute__((ext_vector_type(2)));
typedef float f32x4 __attribute__((ext_vector_type(4)));

#if __has_builtin(__builtin_amdgcn_fdot2)
#define FDOT2(a, b, c) __builtin_amdgcn_fdot2((a), (b), (c), false)
#else
#define FDOT2(a, b, c) fmaf((float)(a)[0], (float)(b)[0], fmaf((float)(a)[1], (float)(b)[1], (c)))
#endif

__device__ inline float waveReduceSum(float v) {
#pragma unroll
    for (int m = 32; m >= 1; m >>= 1) v += __shfl_xor(v, m, 64);
    return v;
}

// ---------------- prep_a: featsh | relprep | seg | pscale | PGf ---------
constexpr int B_FEATSH = 3125;   // N*F/8 / 256
constexpr int B_REL    = 250;    // R/4 (wave per relation)
constexpr int B_SEG    = 1563;
constexpr int B_PSC    = 16;     // P/4 (wave per proxy row)
constexpr int B_PGF    = 64;     // one block per proxy row, coalesced over cols

__global__ __launch_bounds__(256) void prep_a(
        const float* __restrict__ feats, const float* __restrict__ rel_emb,
        const float* __restrict__ attn,  const float* __restrict__ proxy,
        const float* __restrict__ G,     const int* __restrict__ adj,
        _Float16* __restrict__ featsH,   _Float16* __restrict__ relnormH,
        float* __restrict__ dotr, int* __restrict__ nstart, int* __restrict__ nend,
        float* __restrict__ pscale, float* __restrict__ PGf) {
    int b = blockIdx.x, tid = threadIdx.x;
    if (b < B_FEATSH) {
        int idx = b * 256 + tid;
        float4 x0 = ((const float4*)feats)[2 * idx];
        float4 x1 = ((const float4*)feats)[2 * idx + 1];
        f16x8 h;
        h[0] = (_Float16)x0.x; h[1] = (_Float16)x0.y;
        h[2] = (_Float16)x0.z; h[3] = (_Float16)x0.w;
        h[4] = (_Float16)x1.x; h[5] = (_Float16)x1.y;
        h[6] = (_Float16)x1.z; h[7] = (_Float16)x1.w;
        ((f16x8*)featsH)[idx] = h;
    } else if (b < B_FEATSH + B_REL) {
        int r = (b - B_FEATSH) * 4 + (tid >> 6);
        int lane = tid & 63;
        float2 v  = ((const float2*)(rel_emb + (size_t)r * F))[lane];
        float2 a0 = ((const float2*)attn)[lane];
        float2 a1 = ((const float2*)attn)[64 + lane];
        float ss = waveReduceSum(v.x * v.x + v.y * v.y);
        float d0 = waveReduceSum(v.x * a0.x + v.y * a0.y);
        float d1 = waveReduceSum(v.x * a1.x + v.y * a1.y);
        float sc = rsqrtf(fmaxf(ss, 1e-12f));
        f16x2 h; h[0] = (_Float16)(v.x * sc); h[1] = (_Float16)(v.y * sc);
        ((f16x2*)(relnormH + (size_t)r * F))[lane] = h;
        if (lane == 0) { dotr[2 * r] = d0; dotr[2 * r + 1] = d1; }
    } else if (b < B_FEATSH + B_REL + B_SEG) {
        int e = (b - B_FEATSH - B_REL) * 256 + tid;
        if (e < E) {
            int lane = tid & 63;
            int row = ((const int2*)adj)[e].x;
            int prev = __shfl_up(row, 1, 64);
            if (lane == 0) prev = (e > 0) ? ((const int2*)adj)[e - 1].x : -1;
            int nxt = __shfl_down(row, 1, 64);
            if (lane == 63 && e + 1 < E) nxt = ((const int2*)adj)[e + 1].x;
            if (prev != row) {
                nstart[row] = e;
                for (int rr = prev + 1; rr < row; ++rr) { nstart[rr] = e; nend[rr] = e; }
            }
            if (e == E - 1) {
                nend[row] = E;
                for (int rr = row + 1; rr < N; ++rr) { nstart[rr] = E; nend[rr] = E; }
            } else if (nxt != row) {
                nend[row] = e + 1;
            }
        }
    } else if (b < B_FEATSH + B_REL + B_SEG + B_PSC) {
        int j = (b - B_FEATSH - B_REL - B_SEG) * 4 + (tid >> 6);
        int lane = tid & 63;
        float4 p = ((const float4*)(proxy + (size_t)j * OUTC))[lane];
        float ss = waveReduceSum(p.x * p.x + p.y * p.y + p.z * p.z + p.w * p.w);
        if (lane == 0) pscale[j] = rsqrtf(fmaxf(ss, 1e-12f));
    } else {
        // PGf[p][c] = sum_k proxy[p][k] * G[k][c]  (coalesced over c)
        int p = b - (B_FEATSH + B_REL + B_SEG + B_PSC);
        int c = tid;
        float s = 0.f;
        for (int k = 0; k < OUTC; ++k)
            s = fmaf(proxy[(size_t)p * OUTC + k], G[(size_t)k * OUTC + c], s);
        PGf[(size_t)p * OUTC + c] = s;
    }
}

// ---------------- node_aggregate + fragprep (merged grids) -----------------------
// B-frag 16x16x32: lane L holds B[k = kk*32 + (L>>4)*8 + j][n = base + (L&15)]
// Node-agg: 2 edges/group in flight (8 edges/wave-iteration). NOTE (R7 post-mortem):
// mean degree = 8, so 2 slots/group are both real edges; 4-deep slots are clamped
// duplicates -> 50% wasted gathers+VALU (measured +25% duration). Keep 2-deep.
constexpr int NB_NODE = N / 4;   // 12500
constexpr int NB_FRAG = 56;      // 224 64-lane units / 4

__global__ __launch_bounds__(256) void node_frag(
        const _Float16* __restrict__ featsH,
        const _Float16* __restrict__ relnormH,
        const float* __restrict__ dotr,
        const int* __restrict__ adj,
        const int* __restrict__ sidx,
        const float* __restrict__ val,
        const int* __restrict__ nstart,
        const int* __restrict__ nend,
        const float* __restrict__ G,
        const float* __restrict__ proxy,
        const float* __restrict__ pscale,
        const float* __restrict__ PGf,
        _Float16* __restrict__ nf0,
        _Float16* __restrict__ nf1,
        f16x8* __restrict__ Gh, f16x8* __restrict__ pnH,
        f16x8* __restrict__ pxH, f16x8* __restrict__ pgH) {
    if (blockIdx.x >= NB_NODE) {
        // ---- fragprep ----
        int u = (blockIdx.x - NB_NODE) * 4 + (threadIdx.x >> 6);  // 0..223
        int L = threadIdx.x & 63;
        int q = L >> 4, m = L & 15;
        f16x8 h;
        if (u < 128) {                               // Gh: G (256x256)
            int kk = u >> 4, cg = u & 15;
            int n = cg * 16 + m;
#pragma unroll
            for (int j = 0; j < 8; ++j)
                h[j] = (_Float16)G[(size_t)(kk * 32 + q * 8 + j) * OUTC + n];
            Gh[(size_t)u * 64 + L] = h;
        } else if (u < 160) {                        // pnH: l2n(proxy)^T (256x64)
            int idx = u - 128;
            int kk = idx >> 2, w = idx & 3;
            int n = w * 16 + m;
            float sc = pscale[n];
#pragma unroll
            for (int j = 0; j < 8; ++j)
                h[j] = (_Float16)(proxy[(size_t)n * OUTC + kk * 32 + q * 8 + j] * sc);
            pnH[(size_t)idx * 64 + L] = h;
        } else if (u < 192) {                        // pxH: proxy (64x256)
            int idx = u - 160;
            int kk = idx >> 4, cg = idx & 15;
            int n = cg * 16 + m;
#pragma unroll
            for (int j = 0; j < 8; ++j)
                h[j] = (_Float16)proxy[(size_t)(kk * 32 + q * 8 + j) * OUTC + n];
            pxH[(size_t)idx * 64 + L] = h;
        } else {                                     // pgH: -(proxy@G) from PGf
            int idx = u - 192;
            int kk = idx >> 4, cg = idx & 15;
            int n = cg * 16 + m;
#pragma unroll
            for (int j = 0; j < 8; ++j)
                h[j] = (_Float16)(-PGf[(size_t)(kk * 32 + q * 8 + j) * OUTC + n]);
            pgH[(size_t)idx * 64 + L] = h;
        }
        return;
    }
    // ---- node aggregation: single pass, normalize at end ----
    int n = blockIdx.x * 4 + (threadIdx.x >> 6);
    int lane = threadIdx.x & 63;
    int g = lane >> 4, gl = lane & 15;
    int start = nstart[n], end = nend[n];
    const int2* adj2 = (const int2*)adj;
    const int2* sx2  = (const int2*)sidx;
    float A0[8], A1[8];
#pragma unroll
    for (int j = 0; j < 8; ++j) { A0[j] = 0.f; A1[j] = 0.f; }
    float s0 = 0.f, s1 = 0.f;
    for (int e = start + g; e < end; e += 8) {
        int eB = e + 4;
        bool hasB = (eB < end);
        int eBc = hasB ? eB : e;
        int colA = adj2[e].y,   colB = adj2[eBc].y;
        int relA = sx2[e].y,    relB = sx2[eBc].y;
        float vA = val[e],      vB = val[eBc];
        float2 drA = ((const float2*)dotr)[relA];
        float2 drB = ((const float2*)dotr)[relB];
        float wA0 = __expf(vA * drA.x), wA1 = __expf(vA * drA.y);
        float wB0 = hasB ? __expf(vB * drB.x) : 0.f;
        float wB1 = hasB ? __expf(vB * drB.y) : 0.f;
        s0 += wA0 + wB0; s1 += wA1 + wB1;
        f16x8 fAv = ((const f16x8*)(featsH   + (size_t)colA * F))[gl];
        f16x8 rAv = ((const f16x8*)(relnormH + (size_t)relA * F))[gl];
        f16x8 fBv = ((const f16x8*)(featsH   + (size_t)colB * F))[gl];
        f16x8 rBv = ((const f16x8*)(relnormH + (size_t)relB * F))[gl];
        const f16x2* fA2 = (const f16x2*)&fAv;
        const f16x2* rA2 = (const f16x2*)&rAv;
        const f16x2* fB2 = (const f16x2*)&fBv;
        const f16x2* rB2 = (const f16x2*)&rBv;
        float pdA = 0.f, pdB = 0.f;
#pragma unroll
        for (int j = 0; j < 4; ++j) {
            pdA = FDOT2(fA2[j], rA2[j], pdA);
            pdB = FDOT2(fB2[j], rB2[j], pdB);
        }
        pdA += __shfl_xor(pdA, 1, 64); pdB += __shfl_xor(pdB, 1, 64);
        pdA += __shfl_xor(pdA, 2, 64); pdB += __shfl_xor(pdB, 2, 64);
        pdA += __shfl_xor(pdA, 4, 64); pdB += __shfl_xor(pdB, 4, 64);
        pdA += __shfl_xor(pdA, 8, 64); pdB += __shfl_xor(pdB, 8, 64);
        _Float16 tAh = (_Float16)(2.f * pdA), tBh = (_Float16)(2.f * pdB);
        f16x2 tA2; tA2[0] = tAh; tA2[1] = tAh;
        f16x2 tB2; tB2[0] = tBh; tB2[1] = tBh;
#pragma unroll
        for (int j = 0; j < 4; ++j) {
            f16x2 rxA = fA2[j] - tA2 * rA2[j];
            f16x2 rxB = fB2[j] - tB2 * rB2[j];
            float x0 = (float)rxA[0], x1 = (float)rxA[1];
            float y0 = (float)rxB[0], y1 = (float)rxB[1];
            A0[2*j]   = fmaf(wA0, x0, A0[2*j]);   A0[2*j]   = fmaf(wB0, y0, A0[2*j]);
            A0[2*j+1] = fmaf(wA0, x1, A0[2*j+1]); A0[2*j+1] = fmaf(wB0, y1, A0[2*j+1]);
            A1[2*j]   = fmaf(wA1, x0, A1[2*j]);   A1[2*j]   = fmaf(wB1, y0, A1[2*j]);
            A1[2*j+1] = fmaf(wA1, x1, A1[2*j+1]); A1[2*j+1] = fmaf(wB1, y1, A1[2*j+1]);
        }
    }
#pragma unroll
    for (int j = 0; j < 8; ++j) {
        A0[j] += __shfl_xor(A0[j], 16, 64); A0[j] += __shfl_xor(A0[j], 32, 64);
        A1[j] += __shfl_xor(A1[j], 16, 64); A1[j] += __shfl_xor(A1[j], 32, 64);
    }
    s0 += __shfl_xor(s0, 16, 64); s0 += __shfl_xor(s0, 32, 64);
    s1 += __shfl_xor(s1, 16, 64); s1 += __shfl_xor(s1, 32, 64);
    float i0 = (s0 > 0.f) ? 1.f / s0 : 0.f;
    float i1 = (s1 > 0.f) ? 1.f / s1 : 0.f;
    if (g == 0) {
        f16x8 h0, h1;
#pragma unroll
        for (int j = 0; j < 8; ++j) {
            h0[j] = (_Float16)(A0[j] * i0);
            h1[j] = (_Float16)(A1[j] * i1);
        }
        ((f16x8*)(nf0 + (size_t)n * F))[gl] = h0;
        ((f16x8*)(nf1 + (size_t)n * F))[gl] = h1;
    }
}

// ---------------- F: fused build + proxy attention + gate, 64 rows / 512 thr -----
// RT=4, 8 waves [R6 structure] + attH-aliases-attL LDS diet (R9, kept: LDS
// 59.9->50.7 KB, measured Occupancy 29->41%). Nontemporal hints REMOVED
// (R9 post-mortem: nt stores caused 2.5x write amplification, nt loads killed
// inter-block L2 reuse -> FETCH 22->52 MB. Plain loads/stores are correct.)
__global__ __launch_bounds__(512, 6) void proxy_gate(
        const _Float16* __restrict__ featsH,
        const _Float16* __restrict__ nf0,
        const _Float16* __restrict__ nf1,
        const int* __restrict__ neigh,
        const f16x8* __restrict__ pnH,
        const f16x8* __restrict__ pxH,
        const f16x8* __restrict__ Gh,
        const f16x8* __restrict__ pgH,
        float* __restrict__ out) {
    constexpr int RT   = 4;
    constexpr int LDA  = 68;   // f32 logits stride (floats)
    constexpr int LDAH = 72;   // f16 att stride (halves); 144B rows, 16B-aligned
    __shared__ __align__(16) f16x8 outH[RT * 8 * 64];        // 32 KB, A-frag order
    __shared__ __align__(16) float attL[RT * 16 * LDA];      // 17.4 KB (reused as attH)
    __shared__ float scaleL[RT * 16];
    _Float16* attH = (_Float16*)attL;   // alias: attL dead after softmax read phase
    int tid = threadIdx.x;                            // 0..511
    int w = tid >> 6, lane = tid & 63;                // w: 0..7
    int quad = lane >> 4, m = lane & 15;
    size_t row0 = (size_t)blockIdx.x * (RT * 16);

    // ---- build tiles -> f16 A-frags + row 1/norm (2 rows per thread) ----
    {
        int bm0 = tid >> 4, gl = tid & 15;
#pragma unroll
        for (int half = 0; half < 2; ++half) {
            int bm = bm0 + 32 * half;                 // 0..63
            int n = (int)row0 + bm;
            float ss;
            f16x8 h1, h2;
            if (n < N) {
                ss = 0.f;
                h1 = ((const f16x8*)(featsH + (size_t)n * F))[gl];
#pragma unroll
                for (int j = 0; j < 8; ++j) { float x = (float)h1[j]; ss += x * x; }
                int sel = (n < K1) ? neigh[n] : n;
                f16x8 a  = ((const f16x8*)(nf0 + (size_t)n   * F))[gl];
                f16x8 b2 = ((const f16x8*)(nf1 + (size_t)sel * F))[gl];
#pragma unroll
                for (int j = 0; j < 8; ++j) {
                    float v = 0.5f * ((float)a[j] + (float)b2[j]);
                    h2[j] = (_Float16)v;
                    ss += v * v;
                }
            } else {
#pragma unroll
                for (int j = 0; j < 8; ++j) { h1[j] = (_Float16)0.f; h2[j] = (_Float16)0.f; }
                ss = 1.f;
            }
            int t = bm >> 4, r16 = bm & 15;
            outH[(t * 8 +     (gl >> 2)) * 64 + (gl & 3) * 16 + r16] = h1;
            outH[(t * 8 + 4 + (gl >> 2)) * 64 + (gl & 3) * 16 + r16] = h2;
            ss += __shfl_xor(ss, 1, 64); ss += __shfl_xor(ss, 2, 64);
            ss += __shfl_xor(ss, 4, 64); ss += __shfl_xor(ss, 8, 64);
            if (gl == 0) scaleL[bm] = rsqrtf(fmaxf(ss, 1e-12f));
        }
    }
    __syncthreads();

    // ---- logits + z = out@G.  Wave w: logits tasks (tl0,pg) & (tl0+2,pg);
    //      z cols cg in {w, w+8} across all 4 tiles. ----
    int tl0 = w >> 2;       // 0 or 1; second task tile = tl0+2
    int pg = w & 3;
    f32x4 lacc[2] = {(f32x4){0,0,0,0}, (f32x4){0,0,0,0}};
    f32x4 zacc[RT][2];
#pragma unroll
    for (int t = 0; t < RT; ++t)
#pragma unroll
        for (int c = 0; c < 2; ++c) zacc[t][c] = (f32x4){0,0,0,0};
#pragma unroll
    for (int kk = 0; kk < 8; ++kk) {
        f16x8 pb  = pnH[(size_t)(kk * 4 + pg) * 64 + lane];
        f16x8 gb0 = Gh[(size_t)(kk * 16 + w)     * 64 + lane];
        f16x8 gb1 = Gh[(size_t)(kk * 16 + w + 8) * 64 + lane];
        f16x8 a0 = outH[(0 * 8 + kk) * 64 + lane];
        f16x8 a1 = outH[(1 * 8 + kk) * 64 + lane];
        f16x8 a2 = outH[(2 * 8 + kk) * 64 + lane];
        f16x8 a3 = outH[(3 * 8 + kk) * 64 + lane];
        f16x8 aL0 = tl0 ? a1 : a0;   // wave-uniform
        f16x8 aL1 = tl0 ? a3 : a2;
        lacc[0]    = __builtin_amdgcn_mfma_f32_16x16x32_f16(aL0, pb,  lacc[0],    0, 0, 0);
        lacc[1]    = __builtin_amdgcn_mfma_f32_16x16x32_f16(aL1, pb,  lacc[1],    0, 0, 0);
        zacc[0][0] = __builtin_amdgcn_mfma_f32_16x16x32_f16(a0, gb0, zacc[0][0], 0, 0, 0);
        zacc[0][1] = __builtin_amdgcn_mfma_f32_16x16x32_f16(a0, gb1, zacc[0][1], 0, 0, 0);
        zacc[1][0] = __builtin_amdgcn_mfma_f32_16x16x32_f16(a1, gb0, zacc[1][0], 0, 0, 0);
        zacc[1][1] = __builtin_amdgcn_mfma_f32_16x16x32_f16(a1, gb1, zacc[1][1], 0, 0, 0);
        zacc[2][0] = __builtin_amdgcn_mfma_f32_16x16x32_f16(a2, gb0, zacc[2][0], 0, 0, 0);
        zacc[2][1] = __builtin_amdgcn_mfma_f32_16x16x32_f16(a2, gb1, zacc[2][1], 0, 0, 0);
        zacc[3][0] = __builtin_amdgcn_mfma_f32_16x16x32_f16(a3, gb0, zacc[3][0], 0, 0, 0);
        zacc[3][1] = __builtin_amdgcn_mfma_f32_16x16x32_f16(a3, gb1, zacc[3][1], 0, 0, 0);
    }
#pragma unroll
    for (int u = 0; u < 2; ++u) {
        int tile = tl0 + 2 * u;
#pragma unroll
        for (int i = 0; i < 4; ++i) {
            int r = tile * 16 + quad * 4 + i;
            attL[r * LDA + pg * 16 + m] = lacc[u][i] * scaleL[r];
        }
    }
    __syncthreads();

    // ---- softmax over 64 proxies; read attL -> regs; barrier; write f16 attH ----
    {
        float av[8];
#pragma unroll
        for (int i = 0; i < 8; ++i) {
            int r = 8 * w + i;
            float e = __expf(attL[r * LDA + lane]);
            float s = waveReduceSum(e);
            av[i] = e / s;
        }
        __syncthreads();   // all attL reads done before attH overwrites the buffer
#pragma unroll
        for (int i = 0; i < 8; ++i) {
            int r = 8 * w + i;
            attH[r * LDAH + lane] = (_Float16)av[i];
        }
    }
    __syncthreads();

    // ---- q = att@proxy ; z -= att@PG  (wave w: cg in {w, w+8}, 4 tiles) ----
    f32x4 qacc[RT][2];
#pragma unroll
    for (int t = 0; t < RT; ++t)
#pragma unroll
        for (int c = 0; c < 2; ++c) qacc[t][c] = (f32x4){0,0,0,0};
#pragma unroll
    for (int kk = 0; kk < 2; ++kk) {
        f16x8 a[RT];
#pragma unroll
        for (int t = 0; t < RT; ++t)
            a[t] = *(const f16x8*)&attH[(t * 16 + m) * LDAH + kk * 32 + quad * 8];
#pragma unroll
        for (int cgi = 0; cgi < 2; ++cgi) {
            int cg = w + 8 * cgi;
            f16x8 bx = pxH[(size_t)(kk * 16 + cg) * 64 + lane];
            f16x8 bg = pgH[(size_t)(kk * 16 + cg) * 64 + lane];
#pragma unroll
            for (int t = 0; t < RT; ++t) {
                qacc[t][cgi] = __builtin_amdgcn_mfma_f32_16x16x32_f16(a[t], bx, qacc[t][cgi], 0, 0, 0);
                zacc[t][cgi] = __builtin_amdgcn_mfma_f32_16x16x32_f16(a[t], bg, zacc[t][cgi], 0, 0, 0);
            }
        }
    }

    // ---- epilogue: ov from LDS (f16), gate, store ----
    const _Float16* outHs = (const _Float16*)outH;
#pragma unroll
    for (int t = 0; t < RT; ++t) {
        if ((int)row0 + t * 16 >= N) continue;
#pragma unroll
        for (int cgi = 0; cgi < 2; ++cgi) {
            int cg = w + 8 * cgi;
            int c = cg * 16 + m;
            int kkc = cg >> 1;
            int qc = ((cg & 1) << 1) | (m >> 3);
            int j = m & 7;
#pragma unroll
            for (int i = 0; i < 4; ++i) {
                int r15 = quad * 4 + i;
                float ov = (float)outHs[(((t * 8 + kkc) * 64 + qc * 16 + r15) << 3) + j];
                float gate = 1.f / (1.f + __expf(-zacc[t][cgi][i]));
                size_t n = row0 + t * 16 + r15;
                out[n * OUTC + c] = ov - (1.f - gate) * qacc[t][cgi][i];
            }
        }
    }
}

extern "C" void kernel_launch(void* const* d_in, const int* in_sizes, int n_in,
                              void* d_out, int out_size, void* d_ws, size_t ws_size,
                              hipStream_t stream) {
    const float* features   = (const float*)d_in[0];
    const float* rel_emb    = (const float*)d_in[1];
    const float* sparse_val = (const float*)d_in[2];
    const float* attn       = (const float*)d_in[3];
    const float* proxy      = (const float*)d_in[4];
    const float* gateK      = (const float*)d_in[5];
    const int*   adj        = (const int*)d_in[6];
    const int*   sidx       = (const int*)d_in[7];
    const int*   neigh      = (const int*)d_in[9];
    float* out = (float*)d_out;

    char* ws = (char*)d_ws;
    size_t off = 0;
    auto alloc = [&](size_t bytes) -> void* {
        void* p = ws + off;
        off += (bytes + 255) & ~(size_t)255;
        return p;
    };
    _Float16* relnormH = (_Float16*)alloc((size_t)R * F * 2);
    float*    dotr     = (float*)alloc((size_t)R * 2 * 4);
    float*    pscale   = (float*)alloc((size_t)P * 4);
    float*    PGf      = (float*)alloc((size_t)P * OUTC * 4);
    f16x8*    Gh       = (f16x8*)alloc((size_t)128 * 64 * 16);
    f16x8*    pnH      = (f16x8*)alloc((size_t)32 * 64 * 16);
    f16x8*    pxH      = (f16x8*)alloc((size_t)32 * 64 * 16);
    f16x8*    pgH      = (f16x8*)alloc((size_t)32 * 64 * 16);
    _Float16* featsH   = (_Float16*)alloc((size_t)N * F * 2);
    int*      nstart   = (int*)alloc((size_t)N * 4);
    int*      nend     = (int*)alloc((size_t)N * 4);
    _Float16* nf0      = (_Float16*)alloc((size_t)N * F * 2);
    _Float16* nf1      = (_Float16*)alloc((size_t)N * F * 2);

    prep_a<<<B_FEATSH + B_REL + B_SEG + B_PSC + B_PGF, 256, 0, stream>>>(
        features, rel_emb, attn, proxy, gateK, adj,
        featsH, relnormH, dotr, nstart, nend, pscale, PGf);
    node_frag<<<NB_NODE + NB_FRAG, 256, 0, stream>>>(
        featsH, relnormH, dotr, adj, sidx, sparse_val, nstart, nend,
        gateK, proxy, pscale, PGf,
        nf0, nf1, Gh, pnH, pxH, pgH);
    proxy_gate<<<(N + 63) / 64, 512, 0, stream>>>(
        featsH, nf0, nf1, neigh, pnH, pxH, Gh, pgH, out);
}

// Round 12
// 198.249 us; speedup vs baseline: 1.0525x; 1.0093x over previous
//
#include <hip/hip_runtime.h>
#include <math.h>

constexpr int N  = 50000;
constexpr int E  = 400000;
constexpr int R  = 1000;
constexpr int K1 = 1000;
constexpr int F  = 128;
constexpr int OUTC = 256;
constexpr int P  = 64;

typedef _Float16 f16x8 __attribute__((ext_vector_type(8)));
typedef _Float16 f16x4 __attribute__((ext_vector_type(4)));
typedef _Float16 f16x2 __attribute__((ext_vector_type(2)));
typedef float f32x4 __attribute__((ext_vector_type(4)));

#if __has_builtin(__builtin_amdgcn_fdot2)
#define FDOT2(a, b, c) __builtin_amdgcn_fdot2((a), (b), (c), false)
#else
#define FDOT2(a, b, c) fmaf((float)(a)[0], (float)(b)[0], fmaf((float)(a)[1], (float)(b)[1], (c)))
#endif

__device__ inline float waveReduceSum(float v) {
#pragma unroll
    for (int m = 32; m >= 1; m >>= 1) v += __shfl_xor(v, m, 64);
    return v;
}

// ---------------- prep_a: featsh | relprep | seg | pscale | PGf ---------
constexpr int B_FEATSH = 3125;   // N*F/8 / 256
constexpr int B_REL    = 250;    // R/4 (wave per relation)
constexpr int B_SEG    = 1563;
constexpr int B_PSC    = 16;     // P/4 (wave per proxy row)
constexpr int B_PGF    = 64;     // one block per proxy row, coalesced over cols

__global__ __launch_bounds__(256) void prep_a(
        const float* __restrict__ feats, const float* __restrict__ rel_emb,
        const float* __restrict__ attn,  const float* __restrict__ proxy,
        const float* __restrict__ G,     const int* __restrict__ adj,
        _Float16* __restrict__ featsH,   _Float16* __restrict__ relnormH,
        float* __restrict__ dotr, int* __restrict__ nstart, int* __restrict__ nend,
        float* __restrict__ pscale, float* __restrict__ PGf) {
    int b = blockIdx.x, tid = threadIdx.x;
    if (b < B_FEATSH) {
        int idx = b * 256 + tid;
        float4 x0 = ((const float4*)feats)[2 * idx];
        float4 x1 = ((const float4*)feats)[2 * idx + 1];
        f16x8 h;
        h[0] = (_Float16)x0.x; h[1] = (_Float16)x0.y;
        h[2] = (_Float16)x0.z; h[3] = (_Float16)x0.w;
        h[4] = (_Float16)x1.x; h[5] = (_Float16)x1.y;
        h[6] = (_Float16)x1.z; h[7] = (_Float16)x1.w;
        ((f16x8*)featsH)[idx] = h;
    } else if (b < B_FEATSH + B_REL) {
        int r = (b - B_FEATSH) * 4 + (tid >> 6);
        int lane = tid & 63;
        float2 v  = ((const float2*)(rel_emb + (size_t)r * F))[lane];
        float2 a0 = ((const float2*)attn)[lane];
        float2 a1 = ((const float2*)attn)[64 + lane];
        float ss = waveReduceSum(v.x * v.x + v.y * v.y);
        float d0 = waveReduceSum(v.x * a0.x + v.y * a0.y);
        float d1 = waveReduceSum(v.x * a1.x + v.y * a1.y);
        float sc = rsqrtf(fmaxf(ss, 1e-12f));
        f16x2 h; h[0] = (_Float16)(v.x * sc); h[1] = (_Float16)(v.y * sc);
        ((f16x2*)(relnormH + (size_t)r * F))[lane] = h;
        if (lane == 0) { dotr[2 * r] = d0; dotr[2 * r + 1] = d1; }
    } else if (b < B_FEATSH + B_REL + B_SEG) {
        int e = (b - B_FEATSH - B_REL) * 256 + tid;
        if (e < E) {
            int lane = tid & 63;
            int row = ((const int2*)adj)[e].x;
            int prev = __shfl_up(row, 1, 64);
            if (lane == 0) prev = (e > 0) ? ((const int2*)adj)[e - 1].x : -1;
            int nxt = __shfl_down(row, 1, 64);
            if (lane == 63 && e + 1 < E) nxt = ((const int2*)adj)[e + 1].x;
            if (prev != row) {
                nstart[row] = e;
                for (int rr = prev + 1; rr < row; ++rr) { nstart[rr] = e; nend[rr] = e; }
            }
            if (e == E - 1) {
                nend[row] = E;
                for (int rr = row + 1; rr < N; ++rr) { nstart[rr] = E; nend[rr] = E; }
            } else if (nxt != row) {
                nend[row] = e + 1;
            }
        }
    } else if (b < B_FEATSH + B_REL + B_SEG + B_PSC) {
        int j = (b - B_FEATSH - B_REL - B_SEG) * 4 + (tid >> 6);
        int lane = tid & 63;
        float4 p = ((const float4*)(proxy + (size_t)j * OUTC))[lane];
        float ss = waveReduceSum(p.x * p.x + p.y * p.y + p.z * p.z + p.w * p.w);
        if (lane == 0) pscale[j] = rsqrtf(fmaxf(ss, 1e-12f));
    } else {
        // PGf[p][c] = sum_k proxy[p][k] * G[k][c]  (coalesced over c)
        int p = b - (B_FEATSH + B_REL + B_SEG + B_PSC);
        int c = tid;
        float s = 0.f;
        for (int k = 0; k < OUTC; ++k)
            s = fmaf(proxy[(size_t)p * OUTC + k], G[(size_t)k * OUTC + c], s);
        PGf[(size_t)p * OUTC + c] = s;
    }
}

// ---------------- node_aggregate + fragprep (merged grids) -----------------------
// B-frag 16x16x32: lane L holds B[k = kk*32 + (L>>4)*8 + j][n = base + (L&15)]
// Node-agg: 2 edges/group in flight (8 edges/wave-iteration). NOTE (R7 post-mortem):
// mean degree = 8, so 2 slots/group are both real edges; 4-deep slots are clamped
// duplicates -> 50% wasted gathers+VALU (measured +25% duration). Keep 2-deep.
constexpr int NB_NODE = N / 4;   // 12500
constexpr int NB_FRAG = 56;      // 224 64-lane units / 4

__global__ __launch_bounds__(256) void node_frag(
        const _Float16* __restrict__ featsH,
        const _Float16* __restrict__ relnormH,
        const float* __restrict__ dotr,
        const int* __restrict__ adj,
        const int* __restrict__ sidx,
        const float* __restrict__ val,
        const int* __restrict__ nstart,
        const int* __restrict__ nend,
        const float* __restrict__ G,
        const float* __restrict__ proxy,
        const float* __restrict__ pscale,
        const float* __restrict__ PGf,
        _Float16* __restrict__ nf0,
        _Float16* __restrict__ nf1,
        f16x8* __restrict__ Gh, f16x8* __restrict__ pnH,
        f16x8* __restrict__ pxH, f16x8* __restrict__ pgH) {
    if (blockIdx.x >= NB_NODE) {
        // ---- fragprep ----
        int u = (blockIdx.x - NB_NODE) * 4 + (threadIdx.x >> 6);  // 0..223
        int L = threadIdx.x & 63;
        int q = L >> 4, m = L & 15;
        f16x8 h;
        if (u < 128) {                               // Gh: G (256x256)
            int kk = u >> 4, cg = u & 15;
            int n = cg * 16 + m;
#pragma unroll
            for (int j = 0; j < 8; ++j)
                h[j] = (_Float16)G[(size_t)(kk * 32 + q * 8 + j) * OUTC + n];
            Gh[(size_t)u * 64 + L] = h;
        } else if (u < 160) {                        // pnH: l2n(proxy)^T (256x64)
            int idx = u - 128;
            int kk = idx >> 2, w = idx & 3;
            int n = w * 16 + m;
            float sc = pscale[n];
#pragma unroll
            for (int j = 0; j < 8; ++j)
                h[j] = (_Float16)(proxy[(size_t)n * OUTC + kk * 32 + q * 8 + j] * sc);
            pnH[(size_t)idx * 64 + L] = h;
        } else if (u < 192) {                        // pxH: proxy (64x256)
            int idx = u - 160;
            int kk = idx >> 4, cg = idx & 15;
            int n = cg * 16 + m;
#pragma unroll
            for (int j = 0; j < 8; ++j)
                h[j] = (_Float16)proxy[(size_t)(kk * 32 + q * 8 + j) * OUTC + n];
            pxH[(size_t)idx * 64 + L] = h;
        } else {                                     // pgH: -(proxy@G) from PGf
            int idx = u - 192;
            int kk = idx >> 4, cg = idx & 15;
            int n = cg * 16 + m;
#pragma unroll
            for (int j = 0; j < 8; ++j)
                h[j] = (_Float16)(-PGf[(size_t)(kk * 32 + q * 8 + j) * OUTC + n]);
            pgH[(size_t)idx * 64 + L] = h;
        }
        return;
    }
    // ---- node aggregation: single pass, normalize at end ----
    int n = blockIdx.x * 4 + (threadIdx.x >> 6);
    int lane = threadIdx.x & 63;
    int g = lane >> 4, gl = lane & 15;
    int start = nstart[n], end = nend[n];
    const int2* adj2 = (const int2*)adj;
    const int2* sx2  = (const int2*)sidx;
    float A0[8], A1[8];
#pragma unroll
    for (int j = 0; j < 8; ++j) { A0[j] = 0.f; A1[j] = 0.f; }
    float s0 = 0.f, s1 = 0.f;
    for (int e = start + g; e < end; e += 8) {
        int eB = e + 4;
        bool hasB = (eB < end);
        int eBc = hasB ? eB : e;
        int colA = adj2[e].y,   colB = adj2[eBc].y;
        int relA = sx2[e].y,    relB = sx2[eBc].y;
        float vA = val[e],      vB = val[eBc];
        float2 drA = ((const float2*)dotr)[relA];
        float2 drB = ((const float2*)dotr)[relB];
        float wA0 = __expf(vA * drA.x), wA1 = __expf(vA * drA.y);
        float wB0 = hasB ? __expf(vB * drB.x) : 0.f;
        float wB1 = hasB ? __expf(vB * drB.y) : 0.f;
        s0 += wA0 + wB0; s1 += wA1 + wB1;
        f16x8 fAv = ((const f16x8*)(featsH   + (size_t)colA * F))[gl];
        f16x8 rAv = ((const f16x8*)(relnormH + (size_t)relA * F))[gl];
        f16x8 fBv = ((const f16x8*)(featsH   + (size_t)colB * F))[gl];
        f16x8 rBv = ((const f16x8*)(relnormH + (size_t)relB * F))[gl];
        const f16x2* fA2 = (const f16x2*)&fAv;
        const f16x2* rA2 = (const f16x2*)&rAv;
        const f16x2* fB2 = (const f16x2*)&fBv;
        const f16x2* rB2 = (const f16x2*)&rBv;
        float pdA = 0.f, pdB = 0.f;
#pragma unroll
        for (int j = 0; j < 4; ++j) {
            pdA = FDOT2(fA2[j], rA2[j], pdA);
            pdB = FDOT2(fB2[j], rB2[j], pdB);
        }
        pdA += __shfl_xor(pdA, 1, 64); pdB += __shfl_xor(pdB, 1, 64);
        pdA += __shfl_xor(pdA, 2, 64); pdB += __shfl_xor(pdB, 2, 64);
        pdA += __shfl_xor(pdA, 4, 64); pdB += __shfl_xor(pdB, 4, 64);
        pdA += __shfl_xor(pdA, 8, 64); pdB += __shfl_xor(pdB, 8, 64);
        _Float16 tAh = (_Float16)(2.f * pdA), tBh = (_Float16)(2.f * pdB);
        f16x2 tA2; tA2[0] = tAh; tA2[1] = tAh;
        f16x2 tB2; tB2[0] = tBh; tB2[1] = tBh;
#pragma unroll
        for (int j = 0; j < 4; ++j) {
            f16x2 rxA = fA2[j] - tA2 * rA2[j];
            f16x2 rxB = fB2[j] - tB2 * rB2[j];
            float x0 = (float)rxA[0], x1 = (float)rxA[1];
            float y0 = (float)rxB[0], y1 = (float)rxB[1];
            A0[2*j]   = fmaf(wA0, x0, A0[2*j]);   A0[2*j]   = fmaf(wB0, y0, A0[2*j]);
            A0[2*j+1] = fmaf(wA0, x1, A0[2*j+1]); A0[2*j+1] = fmaf(wB0, y1, A0[2*j+1]);
            A1[2*j]   = fmaf(wA1, x0, A1[2*j]);   A1[2*j]   = fmaf(wB1, y0, A1[2*j]);
            A1[2*j+1] = fmaf(wA1, x1, A1[2*j+1]); A1[2*j+1] = fmaf(wB1, y1, A1[2*j+1]);
        }
    }
#pragma unroll
    for (int j = 0; j < 8; ++j) {
        A0[j] += __shfl_xor(A0[j], 16, 64); A0[j] += __shfl_xor(A0[j], 32, 64);
        A1[j] += __shfl_xor(A1[j], 16, 64); A1[j] += __shfl_xor(A1[j], 32, 64);
    }
    s0 += __shfl_xor(s0, 16, 64); s0 += __shfl_xor(s0, 32, 64);
    s1 += __shfl_xor(s1, 16, 64); s1 += __shfl_xor(s1, 32, 64);
    float i0 = (s0 > 0.f) ? 1.f / s0 : 0.f;
    float i1 = (s1 > 0.f) ? 1.f / s1 : 0.f;
    if (g == 0) {
        f16x8 h0, h1;
#pragma unroll
        for (int j = 0; j < 8; ++j) {
            h0[j] = (_Float16)(A0[j] * i0);
            h1[j] = (_Float16)(A1[j] * i1);
        }
        ((f16x8*)(nf0 + (size_t)n * F))[gl] = h0;
        ((f16x8*)(nf1 + (size_t)n * F))[gl] = h1;
    }
}

// ---------------- F: fused build + proxy attention + gate, 64 rows / 512 thr -----
// RT=4, 8 waves, attH-aliases-attL LDS diet (50.7 KB -> 3 blocks/CU, 41% occ).
// R11: z/q column groups cg = {2w, 2w+1} (was {w, w+8}) so each wave owns BOTH
// 64B halves of every 128B L2 line it writes, back-to-back -> no cross-wave
// partial-line RMW amplification (R10 counters: WRITE 53->120 MB at 3 blk/CU).
__global__ __launch_bounds__(512, 6) void proxy_gate(
        const _Float16* __restrict__ featsH,
        const _Float16* __restrict__ nf0,
        const _Float16* __restrict__ nf1,
        const int* __restrict__ neigh,
        const f16x8* __restrict__ pnH,
        const f16x8* __restrict__ pxH,
        const f16x8* __restrict__ Gh,
        const f16x8* __restrict__ pgH,
        float* __restrict__ out) {
    constexpr int RT   = 4;
    constexpr int LDA  = 68;   // f32 logits stride (floats)
    constexpr int LDAH = 72;   // f16 att stride (halves); 144B rows, 16B-aligned
    __shared__ __align__(16) f16x8 outH[RT * 8 * 64];        // 32 KB, A-frag order
    __shared__ __align__(16) float attL[RT * 16 * LDA];      // 17.4 KB (reused as attH)
    __shared__ float scaleL[RT * 16];
    _Float16* attH = (_Float16*)attL;   // alias: attL dead after softmax read phase
    int tid = threadIdx.x;                            // 0..511
    int w = tid >> 6, lane = tid & 63;                // w: 0..7
    int quad = lane >> 4, m = lane & 15;
    size_t row0 = (size_t)blockIdx.x * (RT * 16);

    // ---- build tiles -> f16 A-frags + row 1/norm (2 rows per thread) ----
    {
        int bm0 = tid >> 4, gl = tid & 15;
#pragma unroll
        for (int half = 0; half < 2; ++half) {
            int bm = bm0 + 32 * half;                 // 0..63
            int n = (int)row0 + bm;
            float ss;
            f16x8 h1, h2;
            if (n < N) {
                ss = 0.f;
                h1 = ((const f16x8*)(featsH + (size_t)n * F))[gl];
#pragma unroll
                for (int j = 0; j < 8; ++j) { float x = (float)h1[j]; ss += x * x; }
                int sel = (n < K1) ? neigh[n] : n;
                f16x8 a  = ((const f16x8*)(nf0 + (size_t)n   * F))[gl];
                f16x8 b2 = ((const f16x8*)(nf1 + (size_t)sel * F))[gl];
#pragma unroll
                for (int j = 0; j < 8; ++j) {
                    float v = 0.5f * ((float)a[j] + (float)b2[j]);
                    h2[j] = (_Float16)v;
                    ss += v * v;
                }
            } else {
#pragma unroll
                for (int j = 0; j < 8; ++j) { h1[j] = (_Float16)0.f; h2[j] = (_Float16)0.f; }
                ss = 1.f;
            }
            int t = bm >> 4, r16 = bm & 15;
            outH[(t * 8 +     (gl >> 2)) * 64 + (gl & 3) * 16 + r16] = h1;
            outH[(t * 8 + 4 + (gl >> 2)) * 64 + (gl & 3) * 16 + r16] = h2;
            ss += __shfl_xor(ss, 1, 64); ss += __shfl_xor(ss, 2, 64);
            ss += __shfl_xor(ss, 4, 64); ss += __shfl_xor(ss, 8, 64);
            if (gl == 0) scaleL[bm] = rsqrtf(fmaxf(ss, 1e-12f));
        }
    }
    __syncthreads();

    // ---- logits + z = out@G.  Wave w: logits tasks (tl0,pg) & (tl0+2,pg);
    //      z cols cg in {2w, 2w+1} across all 4 tiles. ----
    int tl0 = w >> 2;       // 0 or 1; second task tile = tl0+2
    int pg = w & 3;
    f32x4 lacc[2] = {(f32x4){0,0,0,0}, (f32x4){0,0,0,0}};
    f32x4 zacc[RT][2];
#pragma unroll
    for (int t = 0; t < RT; ++t)
#pragma unroll
        for (int c = 0; c < 2; ++c) zacc[t][c] = (f32x4){0,0,0,0};
#pragma unroll
    for (int kk = 0; kk < 8; ++kk) {
        f16x8 pb  = pnH[(size_t)(kk * 4 + pg) * 64 + lane];
        f16x8 gb0 = Gh[(size_t)(kk * 16 + 2 * w)     * 64 + lane];
        f16x8 gb1 = Gh[(size_t)(kk * 16 + 2 * w + 1) * 64 + lane];
        f16x8 a0 = outH[(0 * 8 + kk) * 64 + lane];
        f16x8 a1 = outH[(1 * 8 + kk) * 64 + lane];
        f16x8 a2 = outH[(2 * 8 + kk) * 64 + lane];
        f16x8 a3 = outH[(3 * 8 + kk) * 64 + lane];
        f16x8 aL0 = tl0 ? a1 : a0;   // wave-uniform
        f16x8 aL1 = tl0 ? a3 : a2;
        lacc[0]    = __builtin_amdgcn_mfma_f32_16x16x32_f16(aL0, pb,  lacc[0],    0, 0, 0);
        lacc[1]    = __builtin_amdgcn_mfma_f32_16x16x32_f16(aL1, pb,  lacc[1],    0, 0, 0);
        zacc[0][0] = __builtin_amdgcn_mfma_f32_16x16x32_f16(a0, gb0, zacc[0][0], 0, 0, 0);
        zacc[0][1] = __builtin_amdgcn_mfma_f32_16x16x32_f16(a0, gb1, zacc[0][1], 0, 0, 0);
        zacc[1][0] = __builtin_amdgcn_mfma_f32_16x16x32_f16(a1, gb0, zacc[1][0], 0, 0, 0);
        zacc[1][1] = __builtin_amdgcn_mfma_f32_16x16x32_f16(a1, gb1, zacc[1][1], 0, 0, 0);
        zacc[2][0] = __builtin_amdgcn_mfma_f32_16x16x32_f16(a2, gb0, zacc[2][0], 0, 0, 0);
        zacc[2][1] = __builtin_amdgcn_mfma_f32_16x16x32_f16(a2, gb1, zacc[2][1], 0, 0, 0);
        zacc[3][0] = __builtin_amdgcn_mfma_f32_16x16x32_f16(a3, gb0, zacc[3][0], 0, 0, 0);
        zacc[3][1] = __builtin_amdgcn_mfma_f32_16x16x32_f16(a3, gb1, zacc[3][1], 0, 0, 0);
    }
#pragma unroll
    for (int u = 0; u < 2; ++u) {
        int tile = tl0 + 2 * u;
#pragma unroll
        for (int i = 0; i < 4; ++i) {
            int r = tile * 16 + quad * 4 + i;
            attL[r * LDA + pg * 16 + m] = lacc[u][i] * scaleL[r];
        }
    }
    __syncthreads();

    // ---- softmax over 64 proxies; read attL -> regs; barrier; write f16 attH ----
    {
        float av[8];
#pragma unroll
        for (int i = 0; i < 8; ++i) {
            int r = 8 * w + i;
            float e = __expf(attL[r * LDA + lane]);
            float s = waveReduceSum(e);
            av[i] = e / s;
        }
        __syncthreads();   // all attL reads done before attH overwrites the buffer
#pragma unroll
        for (int i = 0; i < 8; ++i) {
            int r = 8 * w + i;
            attH[r * LDAH + lane] = (_Float16)av[i];
        }
    }
    __syncthreads();

    // ---- q = att@proxy ; z -= att@PG  (wave w: cg in {2w, 2w+1}, 4 tiles) ----
    f32x4 qacc[RT][2];
#pragma unroll
    for (int t = 0; t < RT; ++t)
#pragma unroll
        for (int c = 0; c < 2; ++c) qacc[t][c] = (f32x4){0,0,0,0};
#pragma unroll
    for (int kk = 0; kk < 2; ++kk) {
        f16x8 a[RT];
#pragma unroll
        for (int t = 0; t < RT; ++t)
            a[t] = *(const f16x8*)&attH[(t * 16 + m) * LDAH + kk * 32 + quad * 8];
#pragma unroll
        for (int cgi = 0; cgi < 2; ++cgi) {
            int cg = 2 * w + cgi;
            f16x8 bx = pxH[(size_t)(kk * 16 + cg) * 64 + lane];
            f16x8 bg = pgH[(size_t)(kk * 16 + cg) * 64 + lane];
#pragma unroll
            for (int t = 0; t < RT; ++t) {
                qacc[t][cgi] = __builtin_amdgcn_mfma_f32_16x16x32_f16(a[t], bx, qacc[t][cgi], 0, 0, 0);
                zacc[t][cgi] = __builtin_amdgcn_mfma_f32_16x16x32_f16(a[t], bg, zacc[t][cgi], 0, 0, 0);
            }
        }
    }

    // ---- epilogue: ov from LDS (f16), gate, store; cgi inner so the two 64B
    //      halves of each 128B line are written back-to-back by this wave ----
    const _Float16* outHs = (const _Float16*)outH;
#pragma unroll
    for (int t = 0; t < RT; ++t) {
        if ((int)row0 + t * 16 >= N) continue;
#pragma unroll
        for (int i = 0; i < 4; ++i) {
            int r15 = quad * 4 + i;
            size_t n = row0 + t * 16 + r15;
#pragma unroll
            for (int cgi = 0; cgi < 2; ++cgi) {
                int cg = 2 * w + cgi;
                int c = cg * 16 + m;
                int kkc = cg >> 1;
                int qc = ((cg & 1) << 1) | (m >> 3);
                int j = m & 7;
                float ov = (float)outHs[(((t * 8 + kkc) * 64 + qc * 16 + r15) << 3) + j];
                float gate = 1.f / (1.f + __expf(-zacc[t][cgi][i]));
                out[n * OUTC + c] = ov - (1.f - gate) * qacc[t][cgi][i];
            }
        }
    }
}

extern "C" void kernel_launch(void* const* d_in, const int* in_sizes, int n_in,
                              void* d_out, int out_size, void* d_ws, size_t ws_size,
                              hipStream_t stream) {
    const float* features   = (const float*)d_in[0];
    const float* rel_emb    = (const float*)d_in[1];
    const float* sparse_val = (const float*)d_in[2];
    const float* attn       = (const float*)d_in[3];
    const float* proxy      = (const float*)d_in[4];
    const float* gateK      = (const float*)d_in[5];
    const int*   adj        = (const int*)d_in[6];
    const int*   sidx       = (const int*)d_in[7];
    const int*   neigh      = (const int*)d_in[9];
    float* out = (float*)d_out;

    char* ws = (char*)d_ws;
    size_t off = 0;
    auto alloc = [&](size_t bytes) -> void* {
        void* p = ws + off;
        off += (bytes + 255) & ~(size_t)255;
        return p;
    };
    _Float16* relnormH = (_Float16*)alloc((size_t)R * F * 2);
    float*    dotr     = (float*)alloc((size_t)R * 2 * 4);
    float*    pscale   = (float*)alloc((size_t)P * 4);
    float*    PGf      = (float*)alloc((size_t)P * OUTC * 4);
    f16x8*    Gh       = (f16x8*)alloc((size_t)128 * 64 * 16);
    f16x8*    pnH      = (f16x8*)alloc((size_t)32 * 64 * 16);
    f16x8*    pxH      = (f16x8*)alloc((size_t)32 * 64 * 16);
    f16x8*    pgH      = (f16x8*)alloc((size_t)32 * 64 * 16);
    _Float16* featsH   = (_Float16*)alloc((size_t)N * F * 2);
    int*      nstart   = (int*)alloc((size_t)N * 4);
    int*      nend     = (int*)alloc((size_t)N * 4);
    _Float16* nf0      = (_Float16*)alloc((size_t)N * F * 2);
    _Float16* nf1      = (_Float16*)alloc((size_t)N * F * 2);

    prep_a<<<B_FEATSH + B_REL + B_SEG + B_PSC + B_PGF, 256, 0, stream>>>(
        features, rel_emb, attn, proxy, gateK, adj,
        featsH, relnormH, dotr, nstart, nend, pscale, PGf);
    node_frag<<<NB_NODE + NB_FRAG, 256, 0, stream>>>(
        featsH, relnormH, dotr, adj, sidx, sparse_val, nstart, nend,
        gateK, proxy, pscale, PGf,
        nf0, nf1, Gh, pnH, pxH, pgH);
    proxy_gate<<<(N + 63) / 64, 512, 0, stream>>>(
        featsH, nf0, nf1, neigh, pnH, pxH, Gh, pgH, out);
}

// Round 13
// 171.124 us; speedup vs baseline: 1.2193x; 1.1585x over previous
//
#include <hip/hip_runtime.h>
#include <math.h>

constexpr int N  = 50000;
constexpr int E  = 400000;
constexpr int R  = 1000;
constexpr int K1 = 1000;
constexpr int F  = 128;
constexpr int OUTC = 256;
constexpr int P  = 64;

typedef _Float16 f16x8 __attribute__((ext_vector_type(8)));
typedef _Float16 f16x4 __attribute__((ext_vector_type(4)));
typedef _Float16 f16x2 __attribute__((ext_vector_type(2)));
typedef float f32x4 __attribute__((ext_vector_type(4)));

#if __has_builtin(__builtin_amdgcn_fdot2)
#define FDOT2(a, b, c) __builtin_amdgcn_fdot2((a), (b), (c), false)
#else
#define FDOT2(a, b, c) fmaf((float)(a)[0], (float)(b)[0], fmaf((float)(a)[1], (float)(b)[1], (c)))
#endif

__device__ inline float waveReduceSum(float v) {
#pragma unroll
    for (int m = 32; m >= 1; m >>= 1) v += __shfl_xor(v, m, 64);
    return v;
}

// ---------------- prep_a: featsh | relprep | seg | pscale | PGf ---------
constexpr int B_FEATSH = 3125;   // N*F/8 / 256
constexpr int B_REL    = 250;    // R/4 (wave per relation)
constexpr int B_SEG    = 1563;
constexpr int B_PSC    = 16;     // P/4 (wave per proxy row)
constexpr int B_PGF    = 64;     // one block per proxy row, coalesced over cols

__global__ __launch_bounds__(256) void prep_a(
        const float* __restrict__ feats, const float* __restrict__ rel_emb,
        const float* __restrict__ attn,  const float* __restrict__ proxy,
        const float* __restrict__ G,     const int* __restrict__ adj,
        _Float16* __restrict__ featsH,   _Float16* __restrict__ relnormH,
        float* __restrict__ dotr, int* __restrict__ nstart, int* __restrict__ nend,
        float* __restrict__ pscale, float* __restrict__ PGf) {
    int b = blockIdx.x, tid = threadIdx.x;
    if (b < B_FEATSH) {
        int idx = b * 256 + tid;
        float4 x0 = ((const float4*)feats)[2 * idx];
        float4 x1 = ((const float4*)feats)[2 * idx + 1];
        f16x8 h;
        h[0] = (_Float16)x0.x; h[1] = (_Float16)x0.y;
        h[2] = (_Float16)x0.z; h[3] = (_Float16)x0.w;
        h[4] = (_Float16)x1.x; h[5] = (_Float16)x1.y;
        h[6] = (_Float16)x1.z; h[7] = (_Float16)x1.w;
        ((f16x8*)featsH)[idx] = h;
    } else if (b < B_FEATSH + B_REL) {
        int r = (b - B_FEATSH) * 4 + (tid >> 6);
        int lane = tid & 63;
        float2 v  = ((const float2*)(rel_emb + (size_t)r * F))[lane];
        float2 a0 = ((const float2*)attn)[lane];
        float2 a1 = ((const float2*)attn)[64 + lane];
        float ss = waveReduceSum(v.x * v.x + v.y * v.y);
        float d0 = waveReduceSum(v.x * a0.x + v.y * a0.y);
        float d1 = waveReduceSum(v.x * a1.x + v.y * a1.y);
        float sc = rsqrtf(fmaxf(ss, 1e-12f));
        f16x2 h; h[0] = (_Float16)(v.x * sc); h[1] = (_Float16)(v.y * sc);
        ((f16x2*)(relnormH + (size_t)r * F))[lane] = h;
        if (lane == 0) { dotr[2 * r] = d0; dotr[2 * r + 1] = d1; }
    } else if (b < B_FEATSH + B_REL + B_SEG) {
        int e = (b - B_FEATSH - B_REL) * 256 + tid;
        if (e < E) {
            int lane = tid & 63;
            int row = ((const int2*)adj)[e].x;
            int prev = __shfl_up(row, 1, 64);
            if (lane == 0) prev = (e > 0) ? ((const int2*)adj)[e - 1].x : -1;
            int nxt = __shfl_down(row, 1, 64);
            if (lane == 63 && e + 1 < E) nxt = ((const int2*)adj)[e + 1].x;
            if (prev != row) {
                nstart[row] = e;
                for (int rr = prev + 1; rr < row; ++rr) { nstart[rr] = e; nend[rr] = e; }
            }
            if (e == E - 1) {
                nend[row] = E;
                for (int rr = row + 1; rr < N; ++rr) { nstart[rr] = E; nend[rr] = E; }
            } else if (nxt != row) {
                nend[row] = e + 1;
            }
        }
    } else if (b < B_FEATSH + B_REL + B_SEG + B_PSC) {
        int j = (b - B_FEATSH - B_REL - B_SEG) * 4 + (tid >> 6);
        int lane = tid & 63;
        float4 p = ((const float4*)(proxy + (size_t)j * OUTC))[lane];
        float ss = waveReduceSum(p.x * p.x + p.y * p.y + p.z * p.z + p.w * p.w);
        if (lane == 0) pscale[j] = rsqrtf(fmaxf(ss, 1e-12f));
    } else {
        // PGf[p][c] = sum_k proxy[p][k] * G[k][c]  (coalesced over c)
        int p = b - (B_FEATSH + B_REL + B_SEG + B_PSC);
        int c = tid;
        float s = 0.f;
        for (int k = 0; k < OUTC; ++k)
            s = fmaf(proxy[(size_t)p * OUTC + k], G[(size_t)k * OUTC + c], s);
        PGf[(size_t)p * OUTC + c] = s;
    }
}

// ---------------- node_aggregate + fragprep (merged grids) -----------------------
// B-frag 16x16x32: lane L holds B[k = kk*32 + (L>>4)*8 + j][n = base + (L&15)]
// Node-agg: 2 edges/group in flight (8 edges/wave-iteration). NOTE (R7 post-mortem):
// mean degree = 8, so 2 slots/group are both real edges; 4-deep slots are clamped
// duplicates -> 50% wasted gathers+VALU (measured +25% duration). Keep 2-deep.
constexpr int NB_NODE = N / 4;   // 12500
constexpr int NB_FRAG = 56;      // 224 64-lane units / 4

__global__ __launch_bounds__(256) void node_frag(
        const _Float16* __restrict__ featsH,
        const _Float16* __restrict__ relnormH,
        const float* __restrict__ dotr,
        const int* __restrict__ adj,
        const int* __restrict__ sidx,
        const float* __restrict__ val,
        const int* __restrict__ nstart,
        const int* __restrict__ nend,
        const float* __restrict__ G,
        const float* __restrict__ proxy,
        const float* __restrict__ pscale,
        const float* __restrict__ PGf,
        _Float16* __restrict__ nf0,
        _Float16* __restrict__ nf1,
        f16x8* __restrict__ Gh, f16x8* __restrict__ pnH,
        f16x8* __restrict__ pxH, f16x8* __restrict__ pgH) {
    if (blockIdx.x >= NB_NODE) {
        // ---- fragprep ----
        int u = (blockIdx.x - NB_NODE) * 4 + (threadIdx.x >> 6);  // 0..223
        int L = threadIdx.x & 63;
        int q = L >> 4, m = L & 15;
        f16x8 h;
        if (u < 128) {                               // Gh: G (256x256)
            int kk = u >> 4, cg = u & 15;
            int n = cg * 16 + m;
#pragma unroll
            for (int j = 0; j < 8; ++j)
                h[j] = (_Float16)G[(size_t)(kk * 32 + q * 8 + j) * OUTC + n];
            Gh[(size_t)u * 64 + L] = h;
        } else if (u < 160) {                        // pnH: l2n(proxy)^T (256x64)
            int idx = u - 128;
            int kk = idx >> 2, w = idx & 3;
            int n = w * 16 + m;
            float sc = pscale[n];
#pragma unroll
            for (int j = 0; j < 8; ++j)
                h[j] = (_Float16)(proxy[(size_t)n * OUTC + kk * 32 + q * 8 + j] * sc);
            pnH[(size_t)idx * 64 + L] = h;
        } else if (u < 192) {                        // pxH: proxy (64x256)
            int idx = u - 160;
            int kk = idx >> 4, cg = idx & 15;
            int n = cg * 16 + m;
#pragma unroll
            for (int j = 0; j < 8; ++j)
                h[j] = (_Float16)proxy[(size_t)(kk * 32 + q * 8 + j) * OUTC + n];
            pxH[(size_t)idx * 64 + L] = h;
        } else {                                     // pgH: -(proxy@G) from PGf
            int idx = u - 192;
            int kk = idx >> 4, cg = idx & 15;
            int n = cg * 16 + m;
#pragma unroll
            for (int j = 0; j < 8; ++j)
                h[j] = (_Float16)(-PGf[(size_t)(kk * 32 + q * 8 + j) * OUTC + n]);
            pgH[(size_t)idx * 64 + L] = h;
        }
        return;
    }
    // ---- node aggregation: single pass, normalize at end ----
    int n = blockIdx.x * 4 + (threadIdx.x >> 6);
    int lane = threadIdx.x & 63;
    int g = lane >> 4, gl = lane & 15;
    int start = nstart[n], end = nend[n];
    const int2* adj2 = (const int2*)adj;
    const int2* sx2  = (const int2*)sidx;
    float A0[8], A1[8];
#pragma unroll
    for (int j = 0; j < 8; ++j) { A0[j] = 0.f; A1[j] = 0.f; }
    float s0 = 0.f, s1 = 0.f;
    for (int e = start + g; e < end; e += 8) {
        int eB = e + 4;
        bool hasB = (eB < end);
        int eBc = hasB ? eB : e;
        int colA = adj2[e].y,   colB = adj2[eBc].y;
        int relA = sx2[e].y,    relB = sx2[eBc].y;
        float vA = val[e],      vB = val[eBc];
        float2 drA = ((const float2*)dotr)[relA];
        float2 drB = ((const float2*)dotr)[relB];
        float wA0 = __expf(vA * drA.x), wA1 = __expf(vA * drA.y);
        float wB0 = hasB ? __expf(vB * drB.x) : 0.f;
        float wB1 = hasB ? __expf(vB * drB.y) : 0.f;
        s0 += wA0 + wB0; s1 += wA1 + wB1;
        f16x8 fAv = ((const f16x8*)(featsH   + (size_t)colA * F))[gl];
        f16x8 rAv = ((const f16x8*)(relnormH + (size_t)relA * F))[gl];
        f16x8 fBv = ((const f16x8*)(featsH   + (size_t)colB * F))[gl];
        f16x8 rBv = ((const f16x8*)(relnormH + (size_t)relB * F))[gl];
        const f16x2* fA2 = (const f16x2*)&fAv;
        const f16x2* rA2 = (const f16x2*)&rAv;
        const f16x2* fB2 = (const f16x2*)&fBv;
        const f16x2* rB2 = (const f16x2*)&rBv;
        float pdA = 0.f, pdB = 0.f;
#pragma unroll
        for (int j = 0; j < 4; ++j) {
            pdA = FDOT2(fA2[j], rA2[j], pdA);
            pdB = FDOT2(fB2[j], rB2[j], pdB);
        }
        pdA += __shfl_xor(pdA, 1, 64); pdB += __shfl_xor(pdB, 1, 64);
        pdA += __shfl_xor(pdA, 2, 64); pdB += __shfl_xor(pdB, 2, 64);
        pdA += __shfl_xor(pdA, 4, 64); pdB += __shfl_xor(pdB, 4, 64);
        pdA += __shfl_xor(pdA, 8, 64); pdB += __shfl_xor(pdB, 8, 64);
        _Float16 tAh = (_Float16)(2.f * pdA), tBh = (_Float16)(2.f * pdB);
        f16x2 tA2; tA2[0] = tAh; tA2[1] = tAh;
        f16x2 tB2; tB2[0] = tBh; tB2[1] = tBh;
#pragma unroll
        for (int j = 0; j < 4; ++j) {
            f16x2 rxA = fA2[j] - tA2 * rA2[j];
            f16x2 rxB = fB2[j] - tB2 * rB2[j];
            float x0 = (float)rxA[0], x1 = (float)rxA[1];
            float y0 = (float)rxB[0], y1 = (float)rxB[1];
            A0[2*j]   = fmaf(wA0, x0, A0[2*j]);   A0[2*j]   = fmaf(wB0, y0, A0[2*j]);
            A0[2*j+1] = fmaf(wA0, x1, A0[2*j+1]); A0[2*j+1] = fmaf(wB0, y1, A0[2*j+1]);
            A1[2*j]   = fmaf(wA1, x0, A1[2*j]);   A1[2*j]   = fmaf(wB1, y0, A1[2*j]);
            A1[2*j+1] = fmaf(wA1, x1, A1[2*j+1]); A1[2*j+1] = fmaf(wB1, y1, A1[2*j+1]);
        }
    }
#pragma unroll
    for (int j = 0; j < 8; ++j) {
        A0[j] += __shfl_xor(A0[j], 16, 64); A0[j] += __shfl_xor(A0[j], 32, 64);
        A1[j] += __shfl_xor(A1[j], 16, 64); A1[j] += __shfl_xor(A1[j], 32, 64);
    }
    s0 += __shfl_xor(s0, 16, 64); s0 += __shfl_xor(s0, 32, 64);
    s1 += __shfl_xor(s1, 16, 64); s1 += __shfl_xor(s1, 32, 64);
    float i0 = (s0 > 0.f) ? 1.f / s0 : 0.f;
    float i1 = (s1 > 0.f) ? 1.f / s1 : 0.f;
    if (g == 0) {
        f16x8 h0, h1;
#pragma unroll
        for (int j = 0; j < 8; ++j) {
            h0[j] = (_Float16)(A0[j] * i0);
            h1[j] = (_Float16)(A1[j] * i1);
        }
        ((f16x8*)(nf0 + (size_t)n * F))[gl] = h0;
        ((f16x8*)(nf1 + (size_t)n * F))[gl] = h1;
    }
}

// ---------------- F: fused build + proxy attention + gate, 64 rows / 512 thr -----
// RT=4 tiles, 8 waves. EXACT R8 configuration (best measured: 168.2/172.8 total,
// proxy_gate 52 us, FETCH 22 / WRITE 53 MB, VGPR 64).
// LESSON (R9-R11): __launch_bounds__(512,6) capped regs at ~85 -> compiler
// spilled ~40 f32/thread to scratch -> +63 MB WRITE +31 MB FETCH (counters),
// slower despite 41% occupancy. Keep (512,4); check VGPR_Count AND traffic
// together when touching launch bounds.
__global__ __launch_bounds__(512, 4) void proxy_gate(
        const _Float16* __restrict__ featsH,
        const _Float16* __restrict__ nf0,
        const _Float16* __restrict__ nf1,
        const int* __restrict__ neigh,
        const f16x8* __restrict__ pnH,
        const f16x8* __restrict__ pxH,
        const f16x8* __restrict__ Gh,
        const f16x8* __restrict__ pgH,
        float* __restrict__ out) {
    constexpr int RT   = 4;
    constexpr int LDA  = 68;   // f32 logits stride (floats)
    constexpr int LDAH = 72;   // f16 att stride (halves)
    __shared__ __align__(16) f16x8 outH[RT * 8 * 64];        // 32 KB, A-frag order
    __shared__ __align__(16) float attL[RT * 16 * LDA];      // 17.4 KB
    __shared__ __align__(16) _Float16 attH[RT * 16 * LDAH];  // 9.2 KB
    __shared__ float scaleL[RT * 16];
    int tid = threadIdx.x;                            // 0..511
    int w = tid >> 6, lane = tid & 63;                // w: 0..7
    int quad = lane >> 4, m = lane & 15;
    size_t row0 = (size_t)blockIdx.x * (RT * 16);

    // ---- build tiles -> f16 A-frags + row 1/norm (2 rows per thread) ----
    {
        int bm0 = tid >> 4, gl = tid & 15;
#pragma unroll
        for (int half = 0; half < 2; ++half) {
            int bm = bm0 + 32 * half;                 // 0..63
            int n = (int)row0 + bm;
            float ss;
            f16x8 h1, h2;
            if (n < N) {
                ss = 0.f;
                h1 = ((const f16x8*)(featsH + (size_t)n * F))[gl];
#pragma unroll
                for (int j = 0; j < 8; ++j) { float x = (float)h1[j]; ss += x * x; }
                int sel = (n < K1) ? neigh[n] : n;
                f16x8 a  = ((const f16x8*)(nf0 + (size_t)n   * F))[gl];
                f16x8 b2 = ((const f16x8*)(nf1 + (size_t)sel * F))[gl];
#pragma unroll
                for (int j = 0; j < 8; ++j) {
                    float v = 0.5f * ((float)a[j] + (float)b2[j]);
                    h2[j] = (_Float16)v;
                    ss += v * v;
                }
            } else {
#pragma unroll
                for (int j = 0; j < 8; ++j) { h1[j] = (_Float16)0.f; h2[j] = (_Float16)0.f; }
                ss = 1.f;
            }
            int t = bm >> 4, r16 = bm & 15;
            outH[(t * 8 +     (gl >> 2)) * 64 + (gl & 3) * 16 + r16] = h1;
            outH[(t * 8 + 4 + (gl >> 2)) * 64 + (gl & 3) * 16 + r16] = h2;
            ss += __shfl_xor(ss, 1, 64); ss += __shfl_xor(ss, 2, 64);
            ss += __shfl_xor(ss, 4, 64); ss += __shfl_xor(ss, 8, 64);
            if (gl == 0) scaleL[bm] = rsqrtf(fmaxf(ss, 1e-12f));
        }
    }
    __syncthreads();

    // ---- logits + z = out@G.  Wave w: logits tasks (tl0,pg) & (tl0+2,pg);
    //      z cols cg in {w, w+8} across all 4 tiles. ----
    int tl0 = w >> 2;       // 0 or 1; second task tile = tl0+2
    int pg = w & 3;
    f32x4 lacc[2] = {(f32x4){0,0,0,0}, (f32x4){0,0,0,0}};
    f32x4 zacc[RT][2];
#pragma unroll
    for (int t = 0; t < RT; ++t)
#pragma unroll
        for (int c = 0; c < 2; ++c) zacc[t][c] = (f32x4){0,0,0,0};
#pragma unroll
    for (int kk = 0; kk < 8; ++kk) {
        f16x8 pb  = pnH[(size_t)(kk * 4 + pg) * 64 + lane];
        f16x8 gb0 = Gh[(size_t)(kk * 16 + w)     * 64 + lane];
        f16x8 gb1 = Gh[(size_t)(kk * 16 + w + 8) * 64 + lane];
        f16x8 a0 = outH[(0 * 8 + kk) * 64 + lane];
        f16x8 a1 = outH[(1 * 8 + kk) * 64 + lane];
        f16x8 a2 = outH[(2 * 8 + kk) * 64 + lane];
        f16x8 a3 = outH[(3 * 8 + kk) * 64 + lane];
        f16x8 aL0 = tl0 ? a1 : a0;   // wave-uniform
        f16x8 aL1 = tl0 ? a3 : a2;
        lacc[0]    = __builtin_amdgcn_mfma_f32_16x16x32_f16(aL0, pb,  lacc[0],    0, 0, 0);
        lacc[1]    = __builtin_amdgcn_mfma_f32_16x16x32_f16(aL1, pb,  lacc[1],    0, 0, 0);
        zacc[0][0] = __builtin_amdgcn_mfma_f32_16x16x32_f16(a0, gb0, zacc[0][0], 0, 0, 0);
        zacc[0][1] = __builtin_amdgcn_mfma_f32_16x16x32_f16(a0, gb1, zacc[0][1], 0, 0, 0);
        zacc[1][0] = __builtin_amdgcn_mfma_f32_16x16x32_f16(a1, gb0, zacc[1][0], 0, 0, 0);
        zacc[1][1] = __builtin_amdgcn_mfma_f32_16x16x32_f16(a1, gb1, zacc[1][1], 0, 0, 0);
        zacc[2][0] = __builtin_amdgcn_mfma_f32_16x16x32_f16(a2, gb0, zacc[2][0], 0, 0, 0);
        zacc[2][1] = __builtin_amdgcn_mfma_f32_16x16x32_f16(a2, gb1, zacc[2][1], 0, 0, 0);
        zacc[3][0] = __builtin_amdgcn_mfma_f32_16x16x32_f16(a3, gb0, zacc[3][0], 0, 0, 0);
        zacc[3][1] = __builtin_amdgcn_mfma_f32_16x16x32_f16(a3, gb1, zacc[3][1], 0, 0, 0);
    }
#pragma unroll
    for (int u = 0; u < 2; ++u) {
        int tile = tl0 + 2 * u;
#pragma unroll
        for (int i = 0; i < 4; ++i) {
            int r = tile * 16 + quad * 4 + i;
            attL[r * LDA + pg * 16 + m] = lacc[u][i] * scaleL[r];
        }
    }
    __syncthreads();

    // ---- softmax over 64 proxies; 8 rows/wave; write f16 to attH ----
#pragma unroll
    for (int i = 0; i < 8; ++i) {
        int r = 8 * w + i;
        float e = __expf(attL[r * LDA + lane]);
        float s = waveReduceSum(e);
        attH[r * LDAH + lane] = (_Float16)(e / s);
    }
    __syncthreads();

    // ---- q = att@proxy ; z -= att@PG  (wave w: cg in {w, w+8}, 4 tiles) ----
    f32x4 qacc[RT][2];
#pragma unroll
    for (int t = 0; t < RT; ++t)
#pragma unroll
        for (int c = 0; c < 2; ++c) qacc[t][c] = (f32x4){0,0,0,0};
#pragma unroll
    for (int kk = 0; kk < 2; ++kk) {
        f16x8 a[RT];
#pragma unroll
        for (int t = 0; t < RT; ++t)
            a[t] = *(const f16x8*)&attH[(t * 16 + m) * LDAH + kk * 32 + quad * 8];
#pragma unroll
        for (int cgi = 0; cgi < 2; ++cgi) {
            int cg = w + 8 * cgi;
            f16x8 bx = pxH[(size_t)(kk * 16 + cg) * 64 + lane];
            f16x8 bg = pgH[(size_t)(kk * 16 + cg) * 64 + lane];
#pragma unroll
            for (int t = 0; t < RT; ++t) {
                qacc[t][cgi] = __builtin_amdgcn_mfma_f32_16x16x32_f16(a[t], bx, qacc[t][cgi], 0, 0, 0);
                zacc[t][cgi] = __builtin_amdgcn_mfma_f32_16x16x32_f16(a[t], bg, zacc[t][cgi], 0, 0, 0);
            }
        }
    }

    // ---- epilogue: ov from LDS (f16), gate, store ----
    const _Float16* outHs = (const _Float16*)outH;
#pragma unroll
    for (int t = 0; t < RT; ++t) {
        if ((int)row0 + t * 16 >= N) continue;
#pragma unroll
        for (int cgi = 0; cgi < 2; ++cgi) {
            int cg = w + 8 * cgi;
            int c = cg * 16 + m;
            int kkc = cg >> 1;
            int qc = ((cg & 1) << 1) | (m >> 3);
            int j = m & 7;
#pragma unroll
            for (int i = 0; i < 4; ++i) {
                int r15 = quad * 4 + i;
                float ov = (float)outHs[(((t * 8 + kkc) * 64 + qc * 16 + r15) << 3) + j];
                float gate = 1.f / (1.f + __expf(-zacc[t][cgi][i]));
                size_t n = row0 + t * 16 + r15;
                out[n * OUTC + c] = ov - (1.f - gate) * qacc[t][cgi][i];
            }
        }
    }
}

extern "C" void kernel_launch(void* const* d_in, const int* in_sizes, int n_in,
                              void* d_out, int out_size, void* d_ws, size_t ws_size,
                              hipStream_t stream) {
    const float* features   = (const float*)d_in[0];
    const float* rel_emb    = (const float*)d_in[1];
    const float* sparse_val = (const float*)d_in[2];
    const float* attn       = (const float*)d_in[3];
    const float* proxy      = (const float*)d_in[4];
    const float* gateK      = (const float*)d_in[5];
    const int*   adj        = (const int*)d_in[6];
    const int*   sidx       = (const int*)d_in[7];
    const int*   neigh      = (const int*)d_in[9];
    float* out = (float*)d_out;

    char* ws = (char*)d_ws;
    size_t off = 0;
    auto alloc = [&](size_t bytes) -> void* {
        void* p = ws + off;
        off += (bytes + 255) & ~(size_t)255;
        return p;
    };
    _Float16* relnormH = (_Float16*)alloc((size_t)R * F * 2);
    float*    dotr     = (float*)alloc((size_t)R * 2 * 4);
    float*    pscale   = (float*)alloc((size_t)P * 4);
    float*    PGf      = (float*)alloc((size_t)P * OUTC * 4);
    f16x8*    Gh       = (f16x8*)alloc((size_t)128 * 64 * 16);
    f16x8*    pnH      = (f16x8*)alloc((size_t)32 * 64 * 16);
    f16x8*    pxH      = (f16x8*)alloc((size_t)32 * 64 * 16);
    f16x8*    pgH      = (f16x8*)alloc((size_t)32 * 64 * 16);
    _Float16* featsH   = (_Float16*)alloc((size_t)N * F * 2);
    int*      nstart   = (int*)alloc((size_t)N * 4);
    int*      nend     = (int*)alloc((size_t)N * 4);
    _Float16* nf0      = (_Float16*)alloc((size_t)N * F * 2);
    _Float16* nf1      = (_Float16*)alloc((size_t)N * F * 2);

    prep_a<<<B_FEATSH + B_REL + B_SEG + B_PSC + B_PGF, 256, 0, stream>>>(
        features, rel_emb, attn, proxy, gateK, adj,
        featsH, relnormH, dotr, nstart, nend, pscale, PGf);
    node_frag<<<NB_NODE + NB_FRAG, 256, 0, stream>>>(
        featsH, relnormH, dotr, adj, sidx, sparse_val, nstart, nend,
        gateK, proxy, pscale, PGf,
        nf0, nf1, Gh, pnH, pxH, pgH);
    proxy_gate<<<(N + 63) / 64, 512, 0, stream>>>(
        featsH, nf0, nf1, neigh, pnH, pxH, Gh, pgH, out);
}